// Round 7
// baseline (323.118 us; speedup 1.0000x reference)
//
#include <hip/hip_runtime.h>

// ---------------------------------------------------------------------------
// CorrelationalDetector R7 (= R6 with a deeper conv pipeline):
//  convg3: 4 LDS buffers, 3 stages in flight, ONE barrier per K-step,
//  decreasing-tail counted vmcnt (steady state vmcnt(2*NSTG), never 0 until
//  tail), s_setprio(1) around the MFMA cluster.
//  Everything else (conv0/conv1g MFMA, merged halo/pack, xcorr GEMM, BN)
//  identical to R6.
// ---------------------------------------------------------------------------

typedef __bf16 bf16x8 __attribute__((ext_vector_type(8)));
typedef float f32x4 __attribute__((ext_vector_type(4)));
typedef unsigned int u32x4 __attribute__((ext_vector_type(4)));
typedef unsigned int u32x2 __attribute__((ext_vector_type(2)));
typedef unsigned short u16;

#define AS1 __attribute__((address_space(1)))
#define AS3 __attribute__((address_space(3)))

__device__ __forceinline__ u16 f2bf(float v) {
    unsigned u = __float_as_uint(v);
    u += 0x7fffu + ((u >> 16) & 1u);          // RNE
    return (u16)(u >> 16);
}

__device__ __forceinline__ bf16x8 ldb8(const u16* p) {
    return *(const bf16x8*)p;
}

__device__ __forceinline__ bf16x8 zerob8() {
    u32x4 z = {0u, 0u, 0u, 0u};
    bf16x8 r;
    __builtin_memcpy(&r, &z, 16);
    return r;
}

__device__ __forceinline__ void gload16(const u16* g, u16* l) {
    __builtin_amdgcn_global_load_lds((const AS1 void*)g, (AS3 void*)l, 16, 0, 0);
}

template<int N> __device__ __forceinline__ void wait_vm() {
    asm volatile("s_waitcnt vmcnt(%0)" :: "i"(N) : "memory");
}

// barrier with compiler memory fences on both sides (no extra instructions)
__device__ __forceinline__ void bar_mem() {
    asm volatile("" ::: "memory");
    __builtin_amdgcn_s_barrier();
    asm volatile("" ::: "memory");
}

// ---- merged halo zero ------------------------------------------------------
struct HZd { unsigned long long ptr; int B, Hp, Wpx, w8, cum; };
struct HZall { HZd d[8]; int total; };

__global__ __launch_bounds__(256)
void haloz_k(HZall h)
{
    for (int i = blockIdx.x * 256 + threadIdx.x; i < h.total; i += gridDim.x * 256) {
        int di = 0;
        #pragma unroll
        for (int j = 1; j < 8; ++j) if (i >= h.d[j].cum) di = j;
        const HZd D = h.d[di];
        const int loc = i - D.cum;
        const int w = loc % D.w8; int t2 = loc / D.w8;
        const int bord = 2 * D.Wpx + 2 * (D.Hp - 2);
        const int pb = t2 % bord; const int b = t2 / bord;
        int oh, ow;
        if (pb < D.Wpx)            { oh = 0;        ow = pb; }
        else if (pb < 2 * D.Wpx)   { oh = D.Hp - 1; ow = pb - D.Wpx; }
        else { const int q = pb - 2 * D.Wpx; oh = 1 + (q >> 1); ow = (q & 1) ? (D.Wpx - 1) : 0; }
        ((unsigned long long*)D.ptr)[((size_t)b * D.Hp * D.Wpx + (size_t)oh * D.Wpx + ow) * D.w8 + w] = 0ull;
    }
}

// ---- merged weight pack ----------------------------------------------------
__device__ __forceinline__ void packone(const float* W, u16* Wp, int idx,
                                        int ICsh, int Kpad)
{
    const int k = idx % Kpad, oc = idx / Kpad;
    const int tap = k >> ICsh, ic = k & ((1 << ICsh) - 1);
    const float v = (tap < 9) ? W[((size_t)(oc << ICsh) + ic) * 9 + tap] : 0.f;
    Wp[idx] = f2bf(v);
}

__global__ __launch_bounds__(256)
void packall_k(const float* __restrict__ W1, const float* __restrict__ W2,
               const float* __restrict__ W3, const float* __restrict__ W4,
               u16* __restrict__ Wc1, u16* __restrict__ Wp2,
               u16* __restrict__ Wp3, u16* __restrict__ Wp4)
{
    const int i = blockIdx.x * 256 + threadIdx.x;
    if (i < 1024) {                       // Wc1: [16][64], k = ky*16+kx*4+ic
        const int k = i & 63, oc = i >> 6;
        const int ky = k >> 4, kx = (k >> 2) & 3, ic = k & 3;
        const float v = (ky < 3 && kx < 3 && ic < 3) ? W1[oc * 27 + ic * 9 + ky * 3 + kx] : 0.f;
        Wc1[i] = f2bf(v);
    } else if (i < 11264) {               // 1024 + 64*160
        packone(W2, Wp2, i - 1024, 4, 160);
    } else if (i < 84992) {               // + 128*576
        packone(W3, Wp3, i - 11264, 6, 576);
    } else if (i < 379904) {              // + 256*1152
        packone(W4, Wp4, i - 84992, 7, 1152);
    }
}

// ---- L0: IC=3,OC=3, stride2, NCHW fp32 in -> NHWC bf16 4ch padded out ------
__global__ __launch_bounds__(256)
void conv0_k(const float* __restrict__ in, const float* __restrict__ W,
             const float* __restrict__ bias, u16* __restrict__ outP,
             int Btot, int IH, int IW, int OH, int OW)
{
    const int OW4 = OW >> 2;
    const int OWp = OW + 2, OHp = OH + 2;
    const int total = Btot * OH * OW4;
    for (int idx = blockIdx.x * 256 + threadIdx.x; idx < total; idx += gridDim.x * 256) {
        const int ow4 = idx % OW4; int t = idx / OW4;
        const int oh = t % OH;  const int b = t / OH;
        const int owb = ow4 * 4;
        float a0[4], a1[4], a2[4];
        #pragma unroll
        for (int j = 0; j < 4; ++j) { a0[j] = bias[0]; a1[j] = bias[1]; a2[j] = bias[2]; }
        const float* inb = in + (size_t)b * 3 * IH * IW;
        const int xbase = owb * 2 - 1;
        #pragma unroll
        for (int ic = 0; ic < 3; ++ic) {
            const float* ip = inb + (size_t)ic * IH * IW;
            #pragma unroll
            for (int ky = 0; ky < 3; ++ky) {
                const int y = oh * 2 - 1 + ky;
                if ((unsigned)y >= (unsigned)IH) continue;
                const float* rp = ip + (size_t)y * IW;
                float xr[9];
                #pragma unroll
                for (int i2 = 0; i2 < 9; ++i2) {
                    const int x = xbase + i2;
                    xr[i2] = ((unsigned)x < (unsigned)IW) ? rp[x] : 0.f;
                }
                #pragma unroll
                for (int kx = 0; kx < 3; ++kx) {
                    const float w0 = W[0 * 27 + ic * 9 + ky * 3 + kx];
                    const float w1 = W[1 * 27 + ic * 9 + ky * 3 + kx];
                    const float w2 = W[2 * 27 + ic * 9 + ky * 3 + kx];
                    #pragma unroll
                    for (int j = 0; j < 4; ++j) {
                        const float xv = xr[2 * j + kx];
                        a0[j] += xv * w0; a1[j] += xv * w1; a2[j] += xv * w2;
                    }
                }
            }
        }
        u16* op = outP + (((size_t)b * OHp + oh + 1) * OWp + owb + 1) * 4;
        #pragma unroll
        for (int j = 0; j < 4; ++j) {
            u32x2 pk;
            pk[0] = (unsigned)f2bf(fmaxf(a0[j], 0.f)) | ((unsigned)f2bf(fmaxf(a1[j], 0.f)) << 16);
            pk[1] = (unsigned)f2bf(fmaxf(a2[j], 0.f));
            *(u32x2*)(op + j * 4) = pk;
        }
    }
}

// ---- L1 as MFMA GEMM: M=16 oc, K=64 (ky*16+kx*4+ic), N = all px ------------
template<int OWsh, int HWsh>
__global__ __launch_bounds__(256)
void conv1g_k(const u16* __restrict__ inP, const u16* __restrict__ Wc1,
              const float* __restrict__ bias, u16* __restrict__ outP,
              int IWp, int inSS, int OWp, int outSS)
{
    const int w = blockIdx.x * 4 + (threadIdx.x >> 6);
    const int lane = threadIdx.x & 63, lr = lane & 15, lg = lane >> 4;
    const int pxb = w * 64;
    const int OW = 1 << OWsh;

    const bf16x8 av0 = ldb8(Wc1 + lr * 64 + lg * 8);
    const bf16x8 av1 = ldb8(Wc1 + lr * 64 + 32 + lg * 8);
    const int ky0 = lg >> 1,     kxb = (lg & 1) * 2;
    const int ky1 = 2 + (lg >> 1);

    f32x4 acc[4] = {};
    #pragma unroll
    for (int n = 0; n < 4; ++n) {
        const int px = pxb + n * 16 + lr;
        const int b = px >> HWsh;
        const int rem = px & ((1 << HWsh) - 1);
        const int oh = rem >> OWsh, ow = rem & (OW - 1);
        const u16* ib = inP + (size_t)b * inSS + (((size_t)(oh * 2)) * IWp + ow * 2) * 4;
        const bf16x8 bv0 = ldb8(ib + ((size_t)ky0 * IWp + kxb) * 4);
        acc[n] = __builtin_amdgcn_mfma_f32_16x16x32_bf16(av0, bv0, acc[n], 0, 0, 0);
        const bf16x8 bv1 = ldb8(ib + ((size_t)ky1 * IWp + kxb) * 4);
        acc[n] = __builtin_amdgcn_mfma_f32_16x16x32_bf16(av1, bv1, acc[n], 0, 0, 0);
    }

    const float b0 = bias[lg * 4], b1 = bias[lg * 4 + 1],
                b2 = bias[lg * 4 + 2], b3 = bias[lg * 4 + 3];
    #pragma unroll
    for (int n = 0; n < 4; ++n) {
        const int px = pxb + n * 16 + lr;
        const int b = px >> HWsh;
        const int rem = px & ((1 << HWsh) - 1);
        const int oh = rem >> OWsh, ow = rem & (OW - 1);
        const f32x4 a = acc[n];
        u32x2 pk;
        pk[0] = (unsigned)f2bf(fmaxf(a[0] + b0, 0.f)) | ((unsigned)f2bf(fmaxf(a[1] + b1, 0.f)) << 16);
        pk[1] = (unsigned)f2bf(fmaxf(a[2] + b2, 0.f)) | ((unsigned)f2bf(fmaxf(a[3] + b3, 0.f)) << 16);
        u16* op = outP + (size_t)b * outSS + (((size_t)(oh + 1)) * OWp + (ow + 1)) * 16 + lg * 4;
        *(u32x2*)op = pk;
    }
}

// ---- tiled MFMA implicit-GEMM conv3x3: 4-buffer, 3-deep pipeline -----------
// One barrier per K-step. Steady state: 3 stages in flight, wait vmcnt(2*NSTG)
// retires the stage about to be computed. Tail decreases 2*NSTG -> NSTG -> 0.
template<int BM, int BN, int NWM, int NWN, int S>
__global__ __launch_bounds__(256, 2)
void convg3_k(const u16* __restrict__ inP, const u16* __restrict__ Wp,
              const float* __restrict__ bias, u16* __restrict__ out,
              int IC_sh, int IWp, int inSS, int OW_sh, int OWp_o, int outSS,
              int pad_o, int Kreal, int nt, int Kpad, int relu, int n_pt, int OCtot)
{
    constexpr int MF = BM / (NWM * 16);
    constexpr int NF = BN / (NWN * 16);
    constexpr int ASLOT = BM * 4;
    constexpr int BSLOT = BN * 4;
    constexpr int AISS = ASLOT / 256;
    constexpr int BISS = BSLOT / 256;
    constexpr int NSTG = AISS + BISS;

    __shared__ __align__(16) u16 Ab[4][ASLOT * 8];
    __shared__ __align__(16) u16 Bb[4][BSLOT * 8];

    const int t    = threadIdx.x;
    const int wv   = t >> 6, lane = t & 63;
    const int lr   = lane & 15, lg = lane >> 4;
    const int wm   = wv / NWN, wn = wv % NWN;

    const int tilesPerB = (OCtot / BM) * n_pt;
    const int b  = blockIdx.x / tilesPerB;
    const int r0 = blockIdx.x - b * tilesPerB;
    const int mt = r0 / n_pt, pt = r0 - mt * n_pt;
    const int ocb = mt * BM, pxb = pt * BN;
    const int IC = 1 << IC_sh;
    const int OW = 1 << OW_sh;

    const u16* __restrict__ inb = inP + (size_t)b * inSS;

    const u16* agp[AISS];
    #pragma unroll
    for (int i = 0; i < AISS; ++i) {
        const int s = i * 256 + t;
        const int q = s / BM, rr = s - q * BM;
        agp[i] = Wp + (size_t)(ocb + rr) * Kpad + q * 8;
    }
    int bq[BISS]; const u16* bpx[BISS];
    #pragma unroll
    for (int i = 0; i < BISS; ++i) {
        const int s = i * 256 + t;
        const int q = s / BN, rr = s - q * BN;
        const int px = pxb + rr;
        const int oh = px >> OW_sh, ow = px & (OW - 1);
        bq[i] = q;
        bpx[i] = inb + ((size_t)(oh * S) * IWp + ow * S) * IC;
    }

    f32x4 acc[MF][NF] = {};

    auto STAGE = [&](int buf, int kb) {
        #pragma unroll
        for (int i = 0; i < AISS; ++i)
            gload16(agp[i] + kb, &Ab[buf][(size_t)(i * 256 + wv * 64) * 8]);
        #pragma unroll
        for (int i = 0; i < BISS; ++i) {
            const int k = kb + bq[i] * 8;
            const int tap = k >> IC_sh;
            const int ic = k & (IC - 1);
            const int ky = (tap * 11) >> 5, kx = tap - 3 * ky;
            const u16* g = bpx[i] + ((size_t)ky * IWp + kx) * IC + ic;
            if (k >= Kreal) g = inb;           // zero weights there; any in-bounds addr
            gload16(g, &Bb[buf][(size_t)(i * 256 + wv * 64) * 8]);
        }
    };

    // prologue: 3 stages in flight
    STAGE(0, 0);
    if (1 < nt) STAGE(1, 32);
    if (2 < nt) STAGE(2, 64);

    for (int ks = 0; ks < nt; ++ks) {
        const int rem = nt - 1 - ks;          // stages still outstanding beyond ks
        if (rem >= 2)      wait_vm<2 * NSTG>();
        else if (rem == 1) wait_vm<NSTG>();
        else               wait_vm<0>();
        bar_mem();                            // buf[ks&3] ready for all waves;
                                              // all waves done reading buf[(ks-1)&3]
        if (ks + 3 < nt) STAGE((ks + 3) & 3, (ks + 3) * 32);

        const int cur = ks & 3;
        bf16x8 af[MF], bf_[NF];
        #pragma unroll
        for (int m = 0; m < MF; ++m)
            af[m] = ldb8(&Ab[cur][(size_t)(lg * BM + wm * (MF * 16) + m * 16 + lr) * 8]);
        #pragma unroll
        for (int n = 0; n < NF; ++n)
            bf_[n] = ldb8(&Bb[cur][(size_t)(lg * BN + wn * (NF * 16) + n * 16 + lr) * 8]);

        __builtin_amdgcn_s_setprio(1);
        #pragma unroll
        for (int m = 0; m < MF; ++m)
            #pragma unroll
            for (int n = 0; n < NF; ++n)
                acc[m][n] = __builtin_amdgcn_mfma_f32_16x16x32_bf16(af[m], bf_[n], acc[m][n], 0, 0, 0);
        __builtin_amdgcn_s_setprio(0);
    }

    #pragma unroll
    for (int m = 0; m < MF; ++m) {
        const int oc0 = ocb + wm * (MF * 16) + m * 16 + lg * 4;
        const float b0 = bias[oc0], b1 = bias[oc0 + 1], b2 = bias[oc0 + 2], b3 = bias[oc0 + 3];
        #pragma unroll
        for (int n = 0; n < NF; ++n) {
            const int px = pxb + wn * (NF * 16) + n * 16 + lr;
            const int oh = px >> OW_sh, ow = px & (OW - 1);
            const f32x4 a = acc[m][n];
            float v0 = a[0] + b0, v1 = a[1] + b1, v2 = a[2] + b2, v3 = a[3] + b3;
            if (relu) {
                v0 = fmaxf(v0, 0.f); v1 = fmaxf(v1, 0.f);
                v2 = fmaxf(v2, 0.f); v3 = fmaxf(v3, 0.f);
            }
            u32x2 pk;
            pk[0] = (unsigned)f2bf(v0) | ((unsigned)f2bf(v1) << 16);
            pk[1] = (unsigned)f2bf(v2) | ((unsigned)f2bf(v3) << 16);
            u16* op = out + (size_t)b * outSS +
                      (((size_t)(oh + pad_o)) * OWp_o + (ow + pad_o)) * (size_t)OCtot + oc0;
            *(u32x2*)op = pk;
        }
    }
}

// ---- xcorr as batched MFMA GEMM --------------------------------------------
__global__ __launch_bounds__(256)
void xcmf_k(const u16* __restrict__ ffm, const u16* __restrict__ cfm,
            float* __restrict__ R)
{
    const int w    = blockIdx.x * 4 + (threadIdx.x >> 6);   // 1600 waves
    const int lane = threadIdx.x & 63;
    const int lr   = lane & 15, lg = lane >> 4;
    const int b  = w / 25;
    const int tp = w - b * 25;

    const int col0 = tp * 32 + lr;
    const int col1 = col0 + 16;
    const int y0 = col0 / 25, x0 = col0 - y0 * 25;
    const int y1 = col1 / 25, x1 = col1 - y1 * 25;

    const u16* fb = ffm + (size_t)b * 262144;
    const u16* f0 = fb + ((size_t)y0 * 32 + x0) * 256 + lg * 8;
    const u16* f1 = fb + ((size_t)y1 * 32 + x1) * 256 + lg * 8;
    const u16* ab = cfm + (size_t)b * 16384 + (size_t)lr * 2048 + lg * 8;
    const bool arow = (lr < 8);

    f32x4 acc0 = {}, acc1 = {};
    #pragma unroll 4
    for (int kb = 0; kb < 2048; kb += 32) {
        const bf16x8 av = arow ? ldb8(ab + kb) : zerob8();
        const bf16x8 bv0 = ldb8(f0 + kb);
        const bf16x8 bv1 = ldb8(f1 + kb);
        acc0 = __builtin_amdgcn_mfma_f32_16x16x32_bf16(av, bv0, acc0, 0, 0, 0);
        acc1 = __builtin_amdgcn_mfma_f32_16x16x32_bf16(av, bv1, acc1, 0, 0, 0);
    }

    if (lg < 2) {
        float* rb = R + (size_t)b * 6400;
        #pragma unroll
        for (int j = 0; j < 4; ++j) {
            const int d = lg * 4 + j;
            rb[(size_t)d * 800 + col0] = acc0[j];
            rb[(size_t)d * 800 + col1] = acc1[j];
        }
    }
}

// ---- diagonal-band reduce --------------------------------------------------
__global__ __launch_bounds__(256)
void xred_k(const float* __restrict__ R, float* __restrict__ part)
{
    const int i = blockIdx.x * 256 + threadIdx.x;
    if (i >= 40000) return;
    const int b = i / 625;
    const int o = i - b * 625;
    const float* rb = R + (size_t)b * 6400 + o;
    float v = 0.f;
    #pragma unroll
    for (int d = 0; d < 8; ++d) v += rb[(size_t)d * 800 + d * 25];
    part[i] = v;
}

// ---- BatchNorm over all 40000 elements -------------------------------------
__global__ __launch_bounds__(1024)
void bn_k(const float* __restrict__ rmap, const float* __restrict__ gamma,
          const float* __restrict__ beta, float* __restrict__ out)
{
    const int N = 40000;
    const int tid = threadIdx.x;
    __shared__ float rs[1024], rq[1024];
    __shared__ float mean_s, inv_s;
    float s = 0.f, q = 0.f;
    for (int i = tid; i < N; i += 1024) {
        const float v = rmap[i];
        s += v; q += v * v;
    }
    rs[tid] = s; rq[tid] = q;
    __syncthreads();
    for (int off = 512; off > 0; off >>= 1) {
        if (tid < off) { rs[tid] += rs[tid + off]; rq[tid] += rq[tid + off]; }
        __syncthreads();
    }
    if (tid == 0) {
        const float m = rs[0] / (float)N;
        mean_s = m;
        inv_s = rsqrtf(rq[0] / (float)N - m * m + 1e-5f);
    }
    __syncthreads();
    const float g = gamma[0], bt = beta[0];
    for (int i = tid; i < N; i += 1024)
        out[i] = (rmap[i] - mean_s) * inv_s * g + bt;
}

// ---------------------------------------------------------------------------

extern "C" void kernel_launch(void* const* d_in, const int* in_sizes, int n_in,
                              void* d_out, int out_size, void* d_ws, size_t ws_size,
                              hipStream_t stream)
{
    (void)in_sizes; (void)n_in; (void)out_size; (void)ws_size;
    const float* crop  = (const float*)d_in[0];
    const float* frame = (const float*)d_in[1];
    const float* W[5]; const float* bb[5];
    for (int i = 0; i < 5; ++i) { W[i] = (const float*)d_in[2 + 2*i]; bb[i] = (const float*)d_in[3 + 2*i]; }
    const float* gamma = (const float*)d_in[12];
    const float* beta  = (const float*)d_in[13];
    float* out = (float*)d_out;

    unsigned char* ws = (unsigned char*)d_ws;
    // frame pipeline (sizes in BYTES):
    u16*   f0b  = (u16*)(ws + 0);             // [64][130][130][4]   8,652,800 B (dead after fL1)
    u16*   f1p  = (u16*)(ws + 8652800);       // [64][66][66][16]    8,921,088 B (dead after fL2)
    u16*   f2p  = (u16*)(ws + 17573888);      // [64][66][66][64]   35,684,352 B (dead after fL3)
    u16*   f3p  = (u16*)(ws + 53258240);      // [64][34][34][128]  18,939,904 B
    u16*   ffm  = (u16*)(ws + 0);             // [64][32][32][256]  33,554,432 B (aliases dead f0b..f2p)
    // crop pipeline + weights + xcorr after f3p (ends 72,198,144):
    u16*   c0b  = (u16*)(ws + 72198144);      // [64][34][34][4]       591,872 B
    u16*   c1p  = (u16*)(ws + 72790016);      // [64][18][18][16]      663,552 B
    u16*   c2p  = (u16*)(ws + 73453568);      // [64][18][18][64]    2,654,208 B
    u16*   c3p  = (u16*)(ws + 76107776);      // [64][10][10][128]   1,638,400 B
    u16*   cfm  = (u16*)(ws + 77746176);      // [64][8][8][256]     2,097,152 B
    u16*   Wc1  = (u16*)(ws + 79843328);      // [16][64]                2,048 B
    u16*   Wp2  = (u16*)(ws + 79845376);      // [64][160]              20,480 B
    u16*   Wp3  = (u16*)(ws + 79865856);      // [128][576]            147,456 B
    u16*   Wp4  = (u16*)(ws + 80013312);      // [256][1152]           589,824 B
    float* Rbuf = (float*)(ws + 80603136);    // [64][8][800] f32    1,638,400 B
    float* part = (float*)(ws + 82241536);    // [40000] f32           160,000 B

    // ---- one merged halo-zero launch ----
    HZall hz;
    const unsigned long long ptrs[8] = {(unsigned long long)c0b, (unsigned long long)c1p,
        (unsigned long long)c2p, (unsigned long long)c3p, (unsigned long long)f0b,
        (unsigned long long)f1p, (unsigned long long)f2p, (unsigned long long)f3p};
    const int Hps[8] = {34, 18, 18, 10, 130, 66, 66, 34};
    const int w8s[8] = {1, 4, 16, 32, 1, 4, 16, 32};
    int cum = 0;
    for (int i = 0; i < 8; ++i) {
        hz.d[i].ptr = ptrs[i]; hz.d[i].B = 64; hz.d[i].Hp = Hps[i];
        hz.d[i].Wpx = Hps[i]; hz.d[i].w8 = w8s[i]; hz.d[i].cum = cum;
        cum += 64 * (2 * Hps[i] + 2 * (Hps[i] - 2)) * w8s[i];
    }
    hz.total = cum;
    haloz_k<<<1024, 256, 0, stream>>>(hz);

    // ---- one merged weight-pack launch ----
    packall_k<<<1484, 256, 0, stream>>>(W[1], W[2], W[3], W[4], Wc1, Wp2, Wp3, Wp4);

    // ---- crop encoder: 64x64 ->32 ->16 ->16 ->8 ->8 ----
    conv0_k<<<64, 256, 0, stream>>>(crop, W[0], bb[0], c0b, 64, 64, 64, 32, 32);
    conv1g_k<4, 8><<<64, 256, 0, stream>>>(c0b, Wc1, bb[1], c1p, 34, 4624, 18, 5184);
    convg3_k< 64,256,1,4,1><<< 64, 256, 0, stream>>>(c1p, Wp2, bb[2], c2p, 4, 18,  5184, 4, 18, 20736, 1, 144,  5,  160, 1, 1,  64);
    convg3_k<128, 64,4,1,2><<< 64, 256, 0, stream>>>(c2p, Wp3, bb[3], c3p, 6, 18, 20736, 3, 10, 12800, 1, 576, 18,  576, 1, 1, 128);
    convg3_k<256, 64,4,1,1><<< 64, 256, 0, stream>>>(c3p, Wp4, bb[4], cfm, 7, 10, 12800, 3,  8, 16384, 0, 1152, 36, 1152, 0, 1, 256);

    // ---- frame encoder: 256x256 ->128 ->64 ->64 ->32 ->32 ----
    conv0_k<<<1024, 256, 0, stream>>>(frame, W[0], bb[0], f0b, 64, 256, 256, 128, 128);
    conv1g_k<6, 12><<<1024, 256, 0, stream>>>(f0b, Wc1, bb[1], f1p, 130, 67600, 66, 69696);
    convg3_k< 64,256,1,4,1><<<1024, 256, 0, stream>>>(f1p, Wp2, bb[2], f2p, 4, 66,  69696, 6, 66, 278784, 1, 144,  5,  160, 1, 16,  64);
    convg3_k<128,128,2,2,2><<< 512, 256, 0, stream>>>(f2p, Wp3, bb[3], f3p, 6, 66, 278784, 5, 34, 147968, 1, 576, 18,  576, 1, 8, 128);
    convg3_k<128,128,2,2,1><<<1024, 256, 0, stream>>>(f3p, Wp4, bb[4], ffm, 7, 34, 147968, 5, 32, 262144, 0, 1152, 36, 1152, 0, 8, 256);

    // ---- xcorr (MFMA) + band-reduce + BN ----
    xcmf_k<<<400, 256, 0, stream>>>(ffm, cfm, Rbuf);
    xred_k<<<157, 256, 0, stream>>>(Rbuf, part);
    bn_k<<<1, 1024, 0, stream>>>(part, gamma, beta, out);
}

// Round 8
// 317.828 us; speedup vs baseline: 1.0166x; 1.0166x over previous
//
#include <hip/hip_runtime.h>

// ---------------------------------------------------------------------------
// CorrelationalDetector R8:
//  convh_k: 256-wide-tile 8-wave (512t) BK=64 2-phase MFMA conv GEMM for the
//  two big frame layers (fL3, fL4). 4x MFMA per barrier vs R7 -> the
//  stage+vmcnt+barrier critical path (m233: ~72% at small tiles) amortizes.
//  Fragment-order LDS (conflict-free) kept; BK=64 <= IC makes the im2col tap
//  uniform per K-step (address math ~8 ops/step).
//  Crop layers + fL2 stay on convg3 (R7). Heads, xcorr, BN unchanged.
// ---------------------------------------------------------------------------

typedef __bf16 bf16x8 __attribute__((ext_vector_type(8)));
typedef float f32x4 __attribute__((ext_vector_type(4)));
typedef unsigned int u32x4 __attribute__((ext_vector_type(4)));
typedef unsigned int u32x2 __attribute__((ext_vector_type(2)));
typedef unsigned short u16;

#define AS1 __attribute__((address_space(1)))
#define AS3 __attribute__((address_space(3)))

__device__ __forceinline__ u16 f2bf(float v) {
    unsigned u = __float_as_uint(v);
    u += 0x7fffu + ((u >> 16) & 1u);          // RNE
    return (u16)(u >> 16);
}

__device__ __forceinline__ bf16x8 ldb8(const u16* p) {
    return *(const bf16x8*)p;
}

__device__ __forceinline__ bf16x8 zerob8() {
    u32x4 z = {0u, 0u, 0u, 0u};
    bf16x8 r;
    __builtin_memcpy(&r, &z, 16);
    return r;
}

__device__ __forceinline__ void gload16(const u16* g, u16* l) {
    __builtin_amdgcn_global_load_lds((const AS1 void*)g, (AS3 void*)l, 16, 0, 0);
}

template<int N> __device__ __forceinline__ void wait_vm() {
    asm volatile("s_waitcnt vmcnt(%0)" :: "i"(N) : "memory");
}

// barrier with compiler memory fences on both sides (no extra instructions)
__device__ __forceinline__ void bar_mem() {
    asm volatile("" ::: "memory");
    __builtin_amdgcn_s_barrier();
    asm volatile("" ::: "memory");
}

// ---- merged halo zero ------------------------------------------------------
struct HZd { unsigned long long ptr; int B, Hp, Wpx, w8, cum; };
struct HZall { HZd d[8]; int total; };

__global__ __launch_bounds__(256)
void haloz_k(HZall h)
{
    for (int i = blockIdx.x * 256 + threadIdx.x; i < h.total; i += gridDim.x * 256) {
        int di = 0;
        #pragma unroll
        for (int j = 1; j < 8; ++j) if (i >= h.d[j].cum) di = j;
        const HZd D = h.d[di];
        const int loc = i - D.cum;
        const int w = loc % D.w8; int t2 = loc / D.w8;
        const int bord = 2 * D.Wpx + 2 * (D.Hp - 2);
        const int pb = t2 % bord; const int b = t2 / bord;
        int oh, ow;
        if (pb < D.Wpx)            { oh = 0;        ow = pb; }
        else if (pb < 2 * D.Wpx)   { oh = D.Hp - 1; ow = pb - D.Wpx; }
        else { const int q = pb - 2 * D.Wpx; oh = 1 + (q >> 1); ow = (q & 1) ? (D.Wpx - 1) : 0; }
        ((unsigned long long*)D.ptr)[((size_t)b * D.Hp * D.Wpx + (size_t)oh * D.Wpx + ow) * D.w8 + w] = 0ull;
    }
}

// ---- merged weight pack ----------------------------------------------------
__device__ __forceinline__ void packone(const float* W, u16* Wp, int idx,
                                        int ICsh, int Kpad)
{
    const int k = idx % Kpad, oc = idx / Kpad;
    const int tap = k >> ICsh, ic = k & ((1 << ICsh) - 1);
    const float v = (tap < 9) ? W[((size_t)(oc << ICsh) + ic) * 9 + tap] : 0.f;
    Wp[idx] = f2bf(v);
}

__global__ __launch_bounds__(256)
void packall_k(const float* __restrict__ W1, const float* __restrict__ W2,
               const float* __restrict__ W3, const float* __restrict__ W4,
               u16* __restrict__ Wc1, u16* __restrict__ Wp2,
               u16* __restrict__ Wp3, u16* __restrict__ Wp4)
{
    const int i = blockIdx.x * 256 + threadIdx.x;
    if (i < 1024) {                       // Wc1: [16][64], k = ky*16+kx*4+ic
        const int k = i & 63, oc = i >> 6;
        const int ky = k >> 4, kx = (k >> 2) & 3, ic = k & 3;
        const float v = (ky < 3 && kx < 3 && ic < 3) ? W1[oc * 27 + ic * 9 + ky * 3 + kx] : 0.f;
        Wc1[i] = f2bf(v);
    } else if (i < 11264) {               // 1024 + 64*160
        packone(W2, Wp2, i - 1024, 4, 160);
    } else if (i < 84992) {               // + 128*576
        packone(W3, Wp3, i - 11264, 6, 576);
    } else if (i < 379904) {              // + 256*1152
        packone(W4, Wp4, i - 84992, 7, 1152);
    }
}

// ---- L0: IC=3,OC=3, stride2, NCHW fp32 in -> NHWC bf16 4ch padded out ------
__global__ __launch_bounds__(256)
void conv0_k(const float* __restrict__ in, const float* __restrict__ W,
             const float* __restrict__ bias, u16* __restrict__ outP,
             int Btot, int IH, int IW, int OH, int OW)
{
    const int OW4 = OW >> 2;
    const int OWp = OW + 2, OHp = OH + 2;
    const int total = Btot * OH * OW4;
    for (int idx = blockIdx.x * 256 + threadIdx.x; idx < total; idx += gridDim.x * 256) {
        const int ow4 = idx % OW4; int t = idx / OW4;
        const int oh = t % OH;  const int b = t / OH;
        const int owb = ow4 * 4;
        float a0[4], a1[4], a2[4];
        #pragma unroll
        for (int j = 0; j < 4; ++j) { a0[j] = bias[0]; a1[j] = bias[1]; a2[j] = bias[2]; }
        const float* inb = in + (size_t)b * 3 * IH * IW;
        const int xbase = owb * 2 - 1;
        #pragma unroll
        for (int ic = 0; ic < 3; ++ic) {
            const float* ip = inb + (size_t)ic * IH * IW;
            #pragma unroll
            for (int ky = 0; ky < 3; ++ky) {
                const int y = oh * 2 - 1 + ky;
                if ((unsigned)y >= (unsigned)IH) continue;
                const float* rp = ip + (size_t)y * IW;
                float xr[9];
                #pragma unroll
                for (int i2 = 0; i2 < 9; ++i2) {
                    const int x = xbase + i2;
                    xr[i2] = ((unsigned)x < (unsigned)IW) ? rp[x] : 0.f;
                }
                #pragma unroll
                for (int kx = 0; kx < 3; ++kx) {
                    const float w0 = W[0 * 27 + ic * 9 + ky * 3 + kx];
                    const float w1 = W[1 * 27 + ic * 9 + ky * 3 + kx];
                    const float w2 = W[2 * 27 + ic * 9 + ky * 3 + kx];
                    #pragma unroll
                    for (int j = 0; j < 4; ++j) {
                        const float xv = xr[2 * j + kx];
                        a0[j] += xv * w0; a1[j] += xv * w1; a2[j] += xv * w2;
                    }
                }
            }
        }
        u16* op = outP + (((size_t)b * OHp + oh + 1) * OWp + owb + 1) * 4;
        #pragma unroll
        for (int j = 0; j < 4; ++j) {
            u32x2 pk;
            pk[0] = (unsigned)f2bf(fmaxf(a0[j], 0.f)) | ((unsigned)f2bf(fmaxf(a1[j], 0.f)) << 16);
            pk[1] = (unsigned)f2bf(fmaxf(a2[j], 0.f));
            *(u32x2*)(op + j * 4) = pk;
        }
    }
}

// ---- L1 as MFMA GEMM: M=16 oc, K=64 (ky*16+kx*4+ic), N = all px ------------
template<int OWsh, int HWsh>
__global__ __launch_bounds__(256)
void conv1g_k(const u16* __restrict__ inP, const u16* __restrict__ Wc1,
              const float* __restrict__ bias, u16* __restrict__ outP,
              int IWp, int inSS, int OWp, int outSS)
{
    const int w = blockIdx.x * 4 + (threadIdx.x >> 6);
    const int lane = threadIdx.x & 63, lr = lane & 15, lg = lane >> 4;
    const int pxb = w * 64;
    const int OW = 1 << OWsh;

    const bf16x8 av0 = ldb8(Wc1 + lr * 64 + lg * 8);
    const bf16x8 av1 = ldb8(Wc1 + lr * 64 + 32 + lg * 8);
    const int ky0 = lg >> 1,     kxb = (lg & 1) * 2;
    const int ky1 = 2 + (lg >> 1);

    f32x4 acc[4] = {};
    #pragma unroll
    for (int n = 0; n < 4; ++n) {
        const int px = pxb + n * 16 + lr;
        const int b = px >> HWsh;
        const int rem = px & ((1 << HWsh) - 1);
        const int oh = rem >> OWsh, ow = rem & (OW - 1);
        const u16* ib = inP + (size_t)b * inSS + (((size_t)(oh * 2)) * IWp + ow * 2) * 4;
        const bf16x8 bv0 = ldb8(ib + ((size_t)ky0 * IWp + kxb) * 4);
        acc[n] = __builtin_amdgcn_mfma_f32_16x16x32_bf16(av0, bv0, acc[n], 0, 0, 0);
        const bf16x8 bv1 = ldb8(ib + ((size_t)ky1 * IWp + kxb) * 4);
        acc[n] = __builtin_amdgcn_mfma_f32_16x16x32_bf16(av1, bv1, acc[n], 0, 0, 0);
    }

    const float b0 = bias[lg * 4], b1 = bias[lg * 4 + 1],
                b2 = bias[lg * 4 + 2], b3 = bias[lg * 4 + 3];
    #pragma unroll
    for (int n = 0; n < 4; ++n) {
        const int px = pxb + n * 16 + lr;
        const int b = px >> HWsh;
        const int rem = px & ((1 << HWsh) - 1);
        const int oh = rem >> OWsh, ow = rem & (OW - 1);
        const f32x4 a = acc[n];
        u32x2 pk;
        pk[0] = (unsigned)f2bf(fmaxf(a[0] + b0, 0.f)) | ((unsigned)f2bf(fmaxf(a[1] + b1, 0.f)) << 16);
        pk[1] = (unsigned)f2bf(fmaxf(a[2] + b2, 0.f)) | ((unsigned)f2bf(fmaxf(a[3] + b3, 0.f)) << 16);
        u16* op = outP + (size_t)b * outSS + (((size_t)(oh + 1)) * OWp + (ow + 1)) * 16 + lg * 4;
        *(u32x2*)op = pk;
    }
}

// ---- convh: 8-wave 256-wide-tile BK=64 2-phase MFMA conv GEMM --------------
// Requires: BK=64 <= IC (tap uniform per K-step), Kpad = 9*IC (no padded k).
template<int BM, int BN, int NWM, int NWN, int S>
__global__ __launch_bounds__(512, 2)
void convh_k(const u16* __restrict__ inP, const u16* __restrict__ Wp,
             const float* __restrict__ bias, u16* __restrict__ out,
             int IC_sh, int IWp, int inSS, int OW_sh, int OWp_o, int outSS,
             int pad_o, int nt, int Kpad, int relu, int n_pt, int OCtot)
{
    constexpr int MF = BM / (NWM * 16);
    constexpr int NF = BN / (NWN * 16);
    constexpr int ASLOT = BM * 8;          // 16B slots per buffer (BK=64)
    constexpr int BSLOT = BN * 8;
    constexpr int AISS = ASLOT / 512;
    constexpr int BISS = BSLOT / 512;
    constexpr int NSTG = AISS + BISS;

    __shared__ __align__(16) u16 Ab[2][ASLOT * 8];
    __shared__ __align__(16) u16 Bb[2][BSLOT * 8];

    const int t    = threadIdx.x;
    const int wv   = t >> 6, lane = t & 63;
    const int lr   = lane & 15, lg = lane >> 4;
    const int wm   = wv / NWN, wn = wv % NWN;

    const int tilesPerB = (OCtot / BM) * n_pt;
    const int b  = blockIdx.x / tilesPerB;
    const int r0 = blockIdx.x - b * tilesPerB;
    const int mt = r0 / n_pt, pt = r0 - mt * n_pt;
    const int ocb = mt * BM, pxb = pt * BN;
    const int IC = 1 << IC_sh;
    const int OW = 1 << OW_sh;

    const u16* __restrict__ inb = inP + (size_t)b * inSS;

    const u16* agp[AISS];
    #pragma unroll
    for (int i = 0; i < AISS; ++i) {
        const int s = i * 512 + t;
        const int q = s / BM, rr = s - q * BM;
        agp[i] = Wp + (size_t)(ocb + rr) * Kpad + q * 8;
    }
    int bq8[BISS]; const u16* bpx[BISS];
    #pragma unroll
    for (int i = 0; i < BISS; ++i) {
        const int s = i * 512 + t;
        const int q = s / BN, rr = s - q * BN;
        const int px = pxb + rr;
        const int oh = px >> OW_sh, ow = px & (OW - 1);
        bq8[i] = q * 8;
        bpx[i] = inb + ((size_t)(oh * S) * IWp + ow * S) * IC;
    }

    f32x4 acc[MF][NF] = {};

    auto STAGE = [&](int buf, int kb) {
        #pragma unroll
        for (int i = 0; i < AISS; ++i)
            gload16(agp[i] + kb, &Ab[buf][(size_t)(i * 512 + t) * 8]);
        // tap uniform across the whole K-step (BK=64 <= IC)
        const int tap = kb >> IC_sh;
        const int ky = (tap * 11) >> 5, kx = tap - 3 * ky;
        const size_t toff = ((size_t)(ky * IWp + kx) << IC_sh) + (kb & (IC - 1));
        #pragma unroll
        for (int i = 0; i < BISS; ++i)
            gload16(bpx[i] + toff + bq8[i], &Bb[buf][(size_t)(i * 512 + t) * 8]);
    };

    STAGE(0, 0);
    int cur = 0;

    for (int ks = 0; ks < nt; ++ks) {
        if (ks + 1 < nt) {
            STAGE(cur ^ 1, (ks + 1) * 64);
            wait_vm<NSTG>();                // retire current step's loads only
        } else {
            wait_vm<0>();
        }
        bar_mem();                          // buf[cur] ready for all waves

        #pragma unroll
        for (int kk = 0; kk < 2; ++kk) {
            bf16x8 af[MF], bf_[NF];
            #pragma unroll
            for (int m = 0; m < MF; ++m)
                af[m] = ldb8(&Ab[cur][(size_t)((kk * 4 + lg) * BM + wm * (MF * 16) + m * 16 + lr) * 8]);
            #pragma unroll
            for (int n = 0; n < NF; ++n)
                bf_[n] = ldb8(&Bb[cur][(size_t)((kk * 4 + lg) * BN + wn * (NF * 16) + n * 16 + lr) * 8]);
            __builtin_amdgcn_s_setprio(1);
            #pragma unroll
            for (int m = 0; m < MF; ++m)
                #pragma unroll
                for (int n = 0; n < NF; ++n)
                    acc[m][n] = __builtin_amdgcn_mfma_f32_16x16x32_bf16(af[m], bf_[n], acc[m][n], 0, 0, 0);
            __builtin_amdgcn_s_setprio(0);
        }

        bar_mem();                          // all reads of cur done
        cur ^= 1;
    }

    #pragma unroll
    for (int m = 0; m < MF; ++m) {
        const int oc0 = ocb + wm * (MF * 16) + m * 16 + lg * 4;
        const float b0 = bias[oc0], b1 = bias[oc0 + 1], b2 = bias[oc0 + 2], b3 = bias[oc0 + 3];
        #pragma unroll
        for (int n = 0; n < NF; ++n) {
            const int px = pxb + wn * (NF * 16) + n * 16 + lr;
            const int oh = px >> OW_sh, ow = px & (OW - 1);
            const f32x4 a = acc[m][n];
            float v0 = a[0] + b0, v1 = a[1] + b1, v2 = a[2] + b2, v3 = a[3] + b3;
            if (relu) {
                v0 = fmaxf(v0, 0.f); v1 = fmaxf(v1, 0.f);
                v2 = fmaxf(v2, 0.f); v3 = fmaxf(v3, 0.f);
            }
            u32x2 pk;
            pk[0] = (unsigned)f2bf(v0) | ((unsigned)f2bf(v1) << 16);
            pk[1] = (unsigned)f2bf(v2) | ((unsigned)f2bf(v3) << 16);
            u16* op = out + (size_t)b * outSS +
                      (((size_t)(oh + pad_o)) * OWp_o + (ow + pad_o)) * (size_t)OCtot + oc0;
            *(u32x2*)op = pk;
        }
    }
}

// ---- convg3 (R7): 4-buffer 3-deep pipeline, for small layers ---------------
template<int BM, int BN, int NWM, int NWN, int S>
__global__ __launch_bounds__(256, 2)
void convg3_k(const u16* __restrict__ inP, const u16* __restrict__ Wp,
              const float* __restrict__ bias, u16* __restrict__ out,
              int IC_sh, int IWp, int inSS, int OW_sh, int OWp_o, int outSS,
              int pad_o, int Kreal, int nt, int Kpad, int relu, int n_pt, int OCtot)
{
    constexpr int MF = BM / (NWM * 16);
    constexpr int NF = BN / (NWN * 16);
    constexpr int ASLOT = BM * 4;
    constexpr int BSLOT = BN * 4;
    constexpr int AISS = ASLOT / 256;
    constexpr int BISS = BSLOT / 256;
    constexpr int NSTG = AISS + BISS;

    __shared__ __align__(16) u16 Ab[4][ASLOT * 8];
    __shared__ __align__(16) u16 Bb[4][BSLOT * 8];

    const int t    = threadIdx.x;
    const int wv   = t >> 6, lane = t & 63;
    const int lr   = lane & 15, lg = lane >> 4;
    const int wm   = wv / NWN, wn = wv % NWN;

    const int tilesPerB = (OCtot / BM) * n_pt;
    const int b  = blockIdx.x / tilesPerB;
    const int r0 = blockIdx.x - b * tilesPerB;
    const int mt = r0 / n_pt, pt = r0 - mt * n_pt;
    const int ocb = mt * BM, pxb = pt * BN;
    const int IC = 1 << IC_sh;
    const int OW = 1 << OW_sh;

    const u16* __restrict__ inb = inP + (size_t)b * inSS;

    const u16* agp[AISS];
    #pragma unroll
    for (int i = 0; i < AISS; ++i) {
        const int s = i * 256 + t;
        const int q = s / BM, rr = s - q * BM;
        agp[i] = Wp + (size_t)(ocb + rr) * Kpad + q * 8;
    }
    int bq[BISS]; const u16* bpx[BISS];
    #pragma unroll
    for (int i = 0; i < BISS; ++i) {
        const int s = i * 256 + t;
        const int q = s / BN, rr = s - q * BN;
        const int px = pxb + rr;
        const int oh = px >> OW_sh, ow = px & (OW - 1);
        bq[i] = q;
        bpx[i] = inb + ((size_t)(oh * S) * IWp + ow * S) * IC;
    }

    f32x4 acc[MF][NF] = {};

    auto STAGE = [&](int buf, int kb) {
        #pragma unroll
        for (int i = 0; i < AISS; ++i)
            gload16(agp[i] + kb, &Ab[buf][(size_t)(i * 256 + wv * 64) * 8]);
        #pragma unroll
        for (int i = 0; i < BISS; ++i) {
            const int k = kb + bq[i] * 8;
            const int tap = k >> IC_sh;
            const int ic = k & (IC - 1);
            const int ky = (tap * 11) >> 5, kx = tap - 3 * ky;
            const u16* g = bpx[i] + ((size_t)ky * IWp + kx) * IC + ic;
            if (k >= Kreal) g = inb;           // zero weights there; any in-bounds addr
            gload16(g, &Bb[buf][(size_t)(i * 256 + wv * 64) * 8]);
        }
    };

    STAGE(0, 0);
    if (1 < nt) STAGE(1, 32);
    if (2 < nt) STAGE(2, 64);

    for (int ks = 0; ks < nt; ++ks) {
        const int rem = nt - 1 - ks;
        if (rem >= 2)      wait_vm<2 * NSTG>();
        else if (rem == 1) wait_vm<NSTG>();
        else               wait_vm<0>();
        bar_mem();
        if (ks + 3 < nt) STAGE((ks + 3) & 3, (ks + 3) * 32);

        const int cur = ks & 3;
        bf16x8 af[MF], bf_[NF];
        #pragma unroll
        for (int m = 0; m < MF; ++m)
            af[m] = ldb8(&Ab[cur][(size_t)(lg * BM + wm * (MF * 16) + m * 16 + lr) * 8]);
        #pragma unroll
        for (int n = 0; n < NF; ++n)
            bf_[n] = ldb8(&Bb[cur][(size_t)(lg * BN + wn * (NF * 16) + n * 16 + lr) * 8]);

        __builtin_amdgcn_s_setprio(1);
        #pragma unroll
        for (int m = 0; m < MF; ++m)
            #pragma unroll
            for (int n = 0; n < NF; ++n)
                acc[m][n] = __builtin_amdgcn_mfma_f32_16x16x32_bf16(af[m], bf_[n], acc[m][n], 0, 0, 0);
        __builtin_amdgcn_s_setprio(0);
    }

    #pragma unroll
    for (int m = 0; m < MF; ++m) {
        const int oc0 = ocb + wm * (MF * 16) + m * 16 + lg * 4;
        const float b0 = bias[oc0], b1 = bias[oc0 + 1], b2 = bias[oc0 + 2], b3 = bias[oc0 + 3];
        #pragma unroll
        for (int n = 0; n < NF; ++n) {
            const int px = pxb + wn * (NF * 16) + n * 16 + lr;
            const int oh = px >> OW_sh, ow = px & (OW - 1);
            const f32x4 a = acc[m][n];
            float v0 = a[0] + b0, v1 = a[1] + b1, v2 = a[2] + b2, v3 = a[3] + b3;
            if (relu) {
                v0 = fmaxf(v0, 0.f); v1 = fmaxf(v1, 0.f);
                v2 = fmaxf(v2, 0.f); v3 = fmaxf(v3, 0.f);
            }
            u32x2 pk;
            pk[0] = (unsigned)f2bf(v0) | ((unsigned)f2bf(v1) << 16);
            pk[1] = (unsigned)f2bf(v2) | ((unsigned)f2bf(v3) << 16);
            u16* op = out + (size_t)b * outSS +
                      (((size_t)(oh + pad_o)) * OWp_o + (ow + pad_o)) * (size_t)OCtot + oc0;
            *(u32x2*)op = pk;
        }
    }
}

// ---- xcorr as batched MFMA GEMM --------------------------------------------
__global__ __launch_bounds__(256)
void xcmf_k(const u16* __restrict__ ffm, const u16* __restrict__ cfm,
            float* __restrict__ R)
{
    const int w    = blockIdx.x * 4 + (threadIdx.x >> 6);   // 1600 waves
    const int lane = threadIdx.x & 63;
    const int lr   = lane & 15, lg = lane >> 4;
    const int b  = w / 25;
    const int tp = w - b * 25;

    const int col0 = tp * 32 + lr;
    const int col1 = col0 + 16;
    const int y0 = col0 / 25, x0 = col0 - y0 * 25;
    const int y1 = col1 / 25, x1 = col1 - y1 * 25;

    const u16* fb = ffm + (size_t)b * 262144;
    const u16* f0 = fb + ((size_t)y0 * 32 + x0) * 256 + lg * 8;
    const u16* f1 = fb + ((size_t)y1 * 32 + x1) * 256 + lg * 8;
    const u16* ab = cfm + (size_t)b * 16384 + (size_t)lr * 2048 + lg * 8;
    const bool arow = (lr < 8);

    f32x4 acc0 = {}, acc1 = {};
    #pragma unroll 4
    for (int kb = 0; kb < 2048; kb += 32) {
        const bf16x8 av = arow ? ldb8(ab + kb) : zerob8();
        const bf16x8 bv0 = ldb8(f0 + kb);
        const bf16x8 bv1 = ldb8(f1 + kb);
        acc0 = __builtin_amdgcn_mfma_f32_16x16x32_bf16(av, bv0, acc0, 0, 0, 0);
        acc1 = __builtin_amdgcn_mfma_f32_16x16x32_bf16(av, bv1, acc1, 0, 0, 0);
    }

    if (lg < 2) {
        float* rb = R + (size_t)b * 6400;
        #pragma unroll
        for (int j = 0; j < 4; ++j) {
            const int d = lg * 4 + j;
            rb[(size_t)d * 800 + col0] = acc0[j];
            rb[(size_t)d * 800 + col1] = acc1[j];
        }
    }
}

// ---- diagonal-band reduce --------------------------------------------------
__global__ __launch_bounds__(256)
void xred_k(const float* __restrict__ R, float* __restrict__ part)
{
    const int i = blockIdx.x * 256 + threadIdx.x;
    if (i >= 40000) return;
    const int b = i / 625;
    const int o = i - b * 625;
    const float* rb = R + (size_t)b * 6400 + o;
    float v = 0.f;
    #pragma unroll
    for (int d = 0; d < 8; ++d) v += rb[(size_t)d * 800 + d * 25];
    part[i] = v;
}

// ---- BatchNorm over all 40000 elements -------------------------------------
__global__ __launch_bounds__(1024)
void bn_k(const float* __restrict__ rmap, const float* __restrict__ gamma,
          const float* __restrict__ beta, float* __restrict__ out)
{
    const int N = 40000;
    const int tid = threadIdx.x;
    __shared__ float rs[1024], rq[1024];
    __shared__ float mean_s, inv_s;
    float s = 0.f, q = 0.f;
    for (int i = tid; i < N; i += 1024) {
        const float v = rmap[i];
        s += v; q += v * v;
    }
    rs[tid] = s; rq[tid] = q;
    __syncthreads();
    for (int off = 512; off > 0; off >>= 1) {
        if (tid < off) { rs[tid] += rs[tid + off]; rq[tid] += rq[tid + off]; }
        __syncthreads();
    }
    if (tid == 0) {
        const float m = rs[0] / (float)N;
        mean_s = m;
        inv_s = rsqrtf(rq[0] / (float)N - m * m + 1e-5f);
    }
    __syncthreads();
    const float g = gamma[0], bt = beta[0];
    for (int i = tid; i < N; i += 1024)
        out[i] = (rmap[i] - mean_s) * inv_s * g + bt;
}

// ---------------------------------------------------------------------------

extern "C" void kernel_launch(void* const* d_in, const int* in_sizes, int n_in,
                              void* d_out, int out_size, void* d_ws, size_t ws_size,
                              hipStream_t stream)
{
    (void)in_sizes; (void)n_in; (void)out_size; (void)ws_size;
    const float* crop  = (const float*)d_in[0];
    const float* frame = (const float*)d_in[1];
    const float* W[5]; const float* bb[5];
    for (int i = 0; i < 5; ++i) { W[i] = (const float*)d_in[2 + 2*i]; bb[i] = (const float*)d_in[3 + 2*i]; }
    const float* gamma = (const float*)d_in[12];
    const float* beta  = (const float*)d_in[13];
    float* out = (float*)d_out;

    unsigned char* ws = (unsigned char*)d_ws;
    // frame pipeline (sizes in BYTES):
    u16*   f0b  = (u16*)(ws + 0);             // [64][130][130][4]   8,652,800 B (dead after fL1)
    u16*   f1p  = (u16*)(ws + 8652800);       // [64][66][66][16]    8,921,088 B (dead after fL2)
    u16*   f2p  = (u16*)(ws + 17573888);      // [64][66][66][64]   35,684,352 B (dead after fL3)
    u16*   f3p  = (u16*)(ws + 53258240);      // [64][34][34][128]  18,939,904 B
    u16*   ffm  = (u16*)(ws + 0);             // [64][32][32][256]  33,554,432 B (aliases dead f0b..f2p)
    // crop pipeline + weights + xcorr after f3p (ends 72,198,144):
    u16*   c0b  = (u16*)(ws + 72198144);      // [64][34][34][4]       591,872 B
    u16*   c1p  = (u16*)(ws + 72790016);      // [64][18][18][16]      663,552 B
    u16*   c2p  = (u16*)(ws + 73453568);      // [64][18][18][64]    2,654,208 B
    u16*   c3p  = (u16*)(ws + 76107776);      // [64][10][10][128]   1,638,400 B
    u16*   cfm  = (u16*)(ws + 77746176);      // [64][8][8][256]     2,097,152 B
    u16*   Wc1  = (u16*)(ws + 79843328);      // [16][64]                2,048 B
    u16*   Wp2  = (u16*)(ws + 79845376);      // [64][160]              20,480 B
    u16*   Wp3  = (u16*)(ws + 79865856);      // [128][576]            147,456 B
    u16*   Wp4  = (u16*)(ws + 80013312);      // [256][1152]           589,824 B
    float* Rbuf = (float*)(ws + 80603136);    // [64][8][800] f32    1,638,400 B
    float* part = (float*)(ws + 82241536);    // [40000] f32           160,000 B

    // ---- one merged halo-zero launch ----
    HZall hz;
    const unsigned long long ptrs[8] = {(unsigned long long)c0b, (unsigned long long)c1p,
        (unsigned long long)c2p, (unsigned long long)c3p, (unsigned long long)f0b,
        (unsigned long long)f1p, (unsigned long long)f2p, (unsigned long long)f3p};
    const int Hps[8] = {34, 18, 18, 10, 130, 66, 66, 34};
    const int w8s[8] = {1, 4, 16, 32, 1, 4, 16, 32};
    int cum = 0;
    for (int i = 0; i < 8; ++i) {
        hz.d[i].ptr = ptrs[i]; hz.d[i].B = 64; hz.d[i].Hp = Hps[i];
        hz.d[i].Wpx = Hps[i]; hz.d[i].w8 = w8s[i]; hz.d[i].cum = cum;
        cum += 64 * (2 * Hps[i] + 2 * (Hps[i] - 2)) * w8s[i];
    }
    hz.total = cum;
    haloz_k<<<1024, 256, 0, stream>>>(hz);

    // ---- one merged weight-pack launch ----
    packall_k<<<1484, 256, 0, stream>>>(W[1], W[2], W[3], W[4], Wc1, Wp2, Wp3, Wp4);

    // ---- crop encoder: 64x64 ->32 ->16 ->16 ->8 ->8 ----
    conv0_k<<<64, 256, 0, stream>>>(crop, W[0], bb[0], c0b, 64, 64, 64, 32, 32);
    conv1g_k<4, 8><<<64, 256, 0, stream>>>(c0b, Wc1, bb[1], c1p, 34, 4624, 18, 5184);
    convg3_k< 64,256,1,4,1><<< 64, 256, 0, stream>>>(c1p, Wp2, bb[2], c2p, 4, 18,  5184, 4, 18, 20736, 1, 144,  5,  160, 1, 1,  64);
    convg3_k<128, 64,4,1,2><<< 64, 256, 0, stream>>>(c2p, Wp3, bb[3], c3p, 6, 18, 20736, 3, 10, 12800, 1, 576, 18,  576, 1, 1, 128);
    convg3_k<256, 64,4,1,1><<< 64, 256, 0, stream>>>(c3p, Wp4, bb[4], cfm, 7, 10, 12800, 3,  8, 16384, 0, 1152, 36, 1152, 0, 1, 256);

    // ---- frame encoder: 256x256 ->128 ->64 ->64 ->32 ->32 ----
    conv0_k<<<1024, 256, 0, stream>>>(frame, W[0], bb[0], f0b, 64, 256, 256, 128, 128);
    conv1g_k<6, 12><<<1024, 256, 0, stream>>>(f0b, Wc1, bb[1], f1p, 130, 67600, 66, 69696);
    convg3_k< 64,256,1,4,1><<<1024, 256, 0, stream>>>(f1p, Wp2, bb[2], f2p, 4, 66,  69696, 6, 66, 278784, 1, 144,  5,  160, 1, 16,  64);
    //        inP  Wp   bias  out  ICsh IWp inSS    OWsh OWpo outSS  pad nt Kpad relu npt OCtot
    convh_k<128,256,2,4,2><<<256, 512, 0, stream>>>(f2p, Wp3, bb[3], f3p, 6, 66, 278784, 5, 34, 147968, 1,  9,  576, 1, 4, 128);
    convh_k<256,256,2,4,1><<<256, 512, 0, stream>>>(f3p, Wp4, bb[4], ffm, 7, 34, 147968, 5, 32, 262144, 0, 18, 1152, 0, 4, 256);

    // ---- xcorr (MFMA) + band-reduce + BN ----
    xcmf_k<<<400, 256, 0, stream>>>(ffm, cfm, Rbuf);
    xred_k<<<157, 256, 0, stream>>>(Rbuf, part);
    bn_k<<<1, 1024, 0, stream>>>(part, gamma, beta, out);
}

// Round 9
// 314.126 us; speedup vs baseline: 1.0286x; 1.0118x over previous
//
#include <hip/hip_runtime.h>

// ---------------------------------------------------------------------------
// CorrelationalDetector R9:
//  - convh at 128x128/BK64, 8 waves, 64KB LDS -> 2 blocks/CU (cross-block
//    overlap hides the vmcnt+barrier drain; R8's 256-tile was 1 block/CU).
//  - merged crop+frame launches for L0, L1, L2 (head layers no longer leave
//    192 CUs idle; 3 fewer dispatches).
//  Everything else as R8.
// ---------------------------------------------------------------------------

typedef __bf16 bf16x8 __attribute__((ext_vector_type(8)));
typedef float f32x4 __attribute__((ext_vector_type(4)));
typedef unsigned int u32x4 __attribute__((ext_vector_type(4)));
typedef unsigned int u32x2 __attribute__((ext_vector_type(2)));
typedef unsigned short u16;

#define AS1 __attribute__((address_space(1)))
#define AS3 __attribute__((address_space(3)))

__device__ __forceinline__ u16 f2bf(float v) {
    unsigned u = __float_as_uint(v);
    u += 0x7fffu + ((u >> 16) & 1u);          // RNE
    return (u16)(u >> 16);
}

__device__ __forceinline__ bf16x8 ldb8(const u16* p) {
    return *(const bf16x8*)p;
}

__device__ __forceinline__ bf16x8 zerob8() {
    u32x4 z = {0u, 0u, 0u, 0u};
    bf16x8 r;
    __builtin_memcpy(&r, &z, 16);
    return r;
}

__device__ __forceinline__ void gload16(const u16* g, u16* l) {
    __builtin_amdgcn_global_load_lds((const AS1 void*)g, (AS3 void*)l, 16, 0, 0);
}

template<int N> __device__ __forceinline__ void wait_vm() {
    asm volatile("s_waitcnt vmcnt(%0)" :: "i"(N) : "memory");
}

__device__ __forceinline__ void bar_mem() {
    asm volatile("" ::: "memory");
    __builtin_amdgcn_s_barrier();
    asm volatile("" ::: "memory");
}

// per-side geometry for merged / CP-parameterized conv kernels
struct CP { const u16* in; u16* out; int IWp, inSS, OWsh, OWpo, outSS, npt; };

// ---- merged halo zero ------------------------------------------------------
struct HZd { unsigned long long ptr; int B, Hp, Wpx, w8, cum; };
struct HZall { HZd d[8]; int total; };

__global__ __launch_bounds__(256)
void haloz_k(HZall h)
{
    for (int i = blockIdx.x * 256 + threadIdx.x; i < h.total; i += gridDim.x * 256) {
        int di = 0;
        #pragma unroll
        for (int j = 1; j < 8; ++j) if (i >= h.d[j].cum) di = j;
        const HZd D = h.d[di];
        const int loc = i - D.cum;
        const int w = loc % D.w8; int t2 = loc / D.w8;
        const int bord = 2 * D.Wpx + 2 * (D.Hp - 2);
        const int pb = t2 % bord; const int b = t2 / bord;
        int oh, ow;
        if (pb < D.Wpx)            { oh = 0;        ow = pb; }
        else if (pb < 2 * D.Wpx)   { oh = D.Hp - 1; ow = pb - D.Wpx; }
        else { const int q = pb - 2 * D.Wpx; oh = 1 + (q >> 1); ow = (q & 1) ? (D.Wpx - 1) : 0; }
        ((unsigned long long*)D.ptr)[((size_t)b * D.Hp * D.Wpx + (size_t)oh * D.Wpx + ow) * D.w8 + w] = 0ull;
    }
}

// ---- merged weight pack ----------------------------------------------------
__device__ __forceinline__ void packone(const float* W, u16* Wp, int idx,
                                        int ICsh, int Kpad)
{
    const int k = idx % Kpad, oc = idx / Kpad;
    const int tap = k >> ICsh, ic = k & ((1 << ICsh) - 1);
    const float v = (tap < 9) ? W[((size_t)(oc << ICsh) + ic) * 9 + tap] : 0.f;
    Wp[idx] = f2bf(v);
}

__global__ __launch_bounds__(256)
void packall_k(const float* __restrict__ W1, const float* __restrict__ W2,
               const float* __restrict__ W3, const float* __restrict__ W4,
               u16* __restrict__ Wc1, u16* __restrict__ Wp2,
               u16* __restrict__ Wp3, u16* __restrict__ Wp4)
{
    const int i = blockIdx.x * 256 + threadIdx.x;
    if (i < 1024) {                       // Wc1: [16][64], k = ky*16+kx*4+ic
        const int k = i & 63, oc = i >> 6;
        const int ky = k >> 4, kx = (k >> 2) & 3, ic = k & 3;
        const float v = (ky < 3 && kx < 3 && ic < 3) ? W1[oc * 27 + ic * 9 + ky * 3 + kx] : 0.f;
        Wc1[i] = f2bf(v);
    } else if (i < 11264) {               // 1024 + 64*160
        packone(W2, Wp2, i - 1024, 4, 160);
    } else if (i < 84992) {               // + 128*576
        packone(W3, Wp3, i - 11264, 6, 576);
    } else if (i < 379904) {              // + 256*1152
        packone(W4, Wp4, i - 84992, 7, 1152);
    }
}

// ---- L0 body: IC=3,OC=3, stride2, NCHW fp32 in -> NHWC bf16 4ch padded -----
__device__ __forceinline__ void conv0_body(const float* __restrict__ in,
                                           const float* __restrict__ W,
                                           const float* __restrict__ bias,
                                           u16* __restrict__ outP,
                                           int IH, int IW, int OH, int OW, int idx)
{
    const int OW4 = OW >> 2;
    const int OWp = OW + 2, OHp = OH + 2;
    const int ow4 = idx % OW4; int t = idx / OW4;
    const int oh = t % OH;  const int b = t / OH;
    const int owb = ow4 * 4;
    float a0[4], a1[4], a2[4];
    #pragma unroll
    for (int j = 0; j < 4; ++j) { a0[j] = bias[0]; a1[j] = bias[1]; a2[j] = bias[2]; }
    const float* inb = in + (size_t)b * 3 * IH * IW;
    const int xbase = owb * 2 - 1;
    #pragma unroll
    for (int ic = 0; ic < 3; ++ic) {
        const float* ip = inb + (size_t)ic * IH * IW;
        #pragma unroll
        for (int ky = 0; ky < 3; ++ky) {
            const int y = oh * 2 - 1 + ky;
            if ((unsigned)y >= (unsigned)IH) continue;
            const float* rp = ip + (size_t)y * IW;
            float xr[9];
            #pragma unroll
            for (int i2 = 0; i2 < 9; ++i2) {
                const int x = xbase + i2;
                xr[i2] = ((unsigned)x < (unsigned)IW) ? rp[x] : 0.f;
            }
            #pragma unroll
            for (int kx = 0; kx < 3; ++kx) {
                const float w0 = W[0 * 27 + ic * 9 + ky * 3 + kx];
                const float w1 = W[1 * 27 + ic * 9 + ky * 3 + kx];
                const float w2 = W[2 * 27 + ic * 9 + ky * 3 + kx];
                #pragma unroll
                for (int j = 0; j < 4; ++j) {
                    const float xv = xr[2 * j + kx];
                    a0[j] += xv * w0; a1[j] += xv * w1; a2[j] += xv * w2;
                }
            }
        }
    }
    u16* op = outP + (((size_t)b * OHp + oh + 1) * OWp + owb + 1) * 4;
    #pragma unroll
    for (int j = 0; j < 4; ++j) {
        u32x2 pk;
        pk[0] = (unsigned)f2bf(fmaxf(a0[j], 0.f)) | ((unsigned)f2bf(fmaxf(a1[j], 0.f)) << 16);
        pk[1] = (unsigned)f2bf(fmaxf(a2[j], 0.f));
        *(u32x2*)(op + j * 4) = pk;
    }
}

// merged crop+frame L0: blocks [0,64) crop, [64,1088) frame
__global__ __launch_bounds__(256)
void conv0m_k(const float* __restrict__ crop, const float* __restrict__ frame,
              const float* __restrict__ W, const float* __restrict__ bias,
              u16* __restrict__ c0b, u16* __restrict__ f0b)
{
    if (blockIdx.x < 64)
        conv0_body(crop, W, bias, c0b, 64, 64, 32, 32, blockIdx.x * 256 + threadIdx.x);
    else
        conv0_body(frame, W, bias, f0b, 256, 256, 128, 128, (blockIdx.x - 64) * 256 + threadIdx.x);
}

// ---- L1 body: MFMA GEMM M=16 oc, K=64 (ky*16+kx*4+ic) ----------------------
__device__ __forceinline__ void conv1g_body(const u16* __restrict__ inP,
                                            const u16* __restrict__ Wc1,
                                            const float* __restrict__ bias,
                                            u16* __restrict__ outP,
                                            int IWp, int inSS, int OWp, int outSS,
                                            int OWsh, int HWsh, int w, int lane)
{
    const int lr = lane & 15, lg = lane >> 4;
    const int pxb = w * 64;
    const int OW = 1 << OWsh;

    const bf16x8 av0 = ldb8(Wc1 + lr * 64 + lg * 8);
    const bf16x8 av1 = ldb8(Wc1 + lr * 64 + 32 + lg * 8);
    const int ky0 = lg >> 1, kxb = (lg & 1) * 2;
    const int ky1 = 2 + (lg >> 1);

    f32x4 acc[4] = {};
    #pragma unroll
    for (int n = 0; n < 4; ++n) {
        const int px = pxb + n * 16 + lr;
        const int b = px >> HWsh;
        const int rem = px & ((1 << HWsh) - 1);
        const int oh = rem >> OWsh, ow = rem & (OW - 1);
        const u16* ib = inP + (size_t)b * inSS + (((size_t)(oh * 2)) * IWp + ow * 2) * 4;
        const bf16x8 bv0 = ldb8(ib + ((size_t)ky0 * IWp + kxb) * 4);
        acc[n] = __builtin_amdgcn_mfma_f32_16x16x32_bf16(av0, bv0, acc[n], 0, 0, 0);
        const bf16x8 bv1 = ldb8(ib + ((size_t)ky1 * IWp + kxb) * 4);
        acc[n] = __builtin_amdgcn_mfma_f32_16x16x32_bf16(av1, bv1, acc[n], 0, 0, 0);
    }

    const float b0 = bias[lg * 4], b1 = bias[lg * 4 + 1],
                b2 = bias[lg * 4 + 2], b3 = bias[lg * 4 + 3];
    #pragma unroll
    for (int n = 0; n < 4; ++n) {
        const int px = pxb + n * 16 + lr;
        const int b = px >> HWsh;
        const int rem = px & ((1 << HWsh) - 1);
        const int oh = rem >> OWsh, ow = rem & (OW - 1);
        const f32x4 a = acc[n];
        u32x2 pk;
        pk[0] = (unsigned)f2bf(fmaxf(a[0] + b0, 0.f)) | ((unsigned)f2bf(fmaxf(a[1] + b1, 0.f)) << 16);
        pk[1] = (unsigned)f2bf(fmaxf(a[2] + b2, 0.f)) | ((unsigned)f2bf(fmaxf(a[3] + b3, 0.f)) << 16);
        u16* op = outP + (size_t)b * outSS + (((size_t)(oh + 1)) * OWp + (ow + 1)) * 16 + lg * 4;
        *(u32x2*)op = pk;
    }
}

// merged crop+frame L1: blocks [0,64) crop, [64,1088) frame
__global__ __launch_bounds__(256)
void conv1m_k(const u16* __restrict__ c0b, u16* __restrict__ c1p,
              const u16* __restrict__ f0b, u16* __restrict__ f1p,
              const u16* __restrict__ Wc1, const float* __restrict__ bias)
{
    const int wv = threadIdx.x >> 6, lane = threadIdx.x & 63;
    if (blockIdx.x < 64)
        conv1g_body(c0b, Wc1, bias, c1p, 34, 4624, 18, 5184, 4, 8, blockIdx.x * 4 + wv, lane);
    else
        conv1g_body(f0b, Wc1, bias, f1p, 130, 67600, 66, 69696, 6, 12, (blockIdx.x - 64) * 4 + wv, lane);
}

// ---- convh: 8-wave 128x128 BK=64 2-phase MFMA conv GEMM, 2 blocks/CU -------
// Requires: BK=64 <= IC (tap uniform per K-step), Kpad = 9*IC.
template<int BM, int BN, int NWM, int NWN, int S>
__global__ __launch_bounds__(512, 4)
void convh_k(const u16* __restrict__ inP, const u16* __restrict__ Wp,
             const float* __restrict__ bias, u16* __restrict__ out,
             int IC_sh, int IWp, int inSS, int OW_sh, int OWp_o, int outSS,
             int pad_o, int nt, int Kpad, int relu, int n_pt, int OCtot)
{
    constexpr int MF = BM / (NWM * 16);
    constexpr int NF = BN / (NWN * 16);
    constexpr int ASLOT = BM * 8;          // 16B slots per buffer (BK=64)
    constexpr int BSLOT = BN * 8;
    constexpr int AISS = ASLOT / 512;
    constexpr int BISS = BSLOT / 512;
    constexpr int NSTG = AISS + BISS;

    __shared__ __align__(16) u16 Ab[2][ASLOT * 8];
    __shared__ __align__(16) u16 Bb[2][BSLOT * 8];

    const int t    = threadIdx.x;
    const int wv   = t >> 6, lane = t & 63;
    const int lr   = lane & 15, lg = lane >> 4;
    const int wm   = wv / NWN, wn = wv % NWN;

    const int tilesPerB = (OCtot / BM) * n_pt;
    const int b  = blockIdx.x / tilesPerB;
    const int r0 = blockIdx.x - b * tilesPerB;
    const int mt = r0 / n_pt, pt = r0 - mt * n_pt;
    const int ocb = mt * BM, pxb = pt * BN;
    const int IC = 1 << IC_sh;
    const int OW = 1 << OW_sh;

    const u16* __restrict__ inb = inP + (size_t)b * inSS;

    const u16* agp[AISS];
    #pragma unroll
    for (int i = 0; i < AISS; ++i) {
        const int s = i * 512 + t;
        const int q = s / BM, rr = s - q * BM;
        agp[i] = Wp + (size_t)(ocb + rr) * Kpad + q * 8;
    }
    int bq8[BISS]; const u16* bpx[BISS];
    #pragma unroll
    for (int i = 0; i < BISS; ++i) {
        const int s = i * 512 + t;
        const int q = s / BN, rr = s - q * BN;
        const int px = pxb + rr;
        const int oh = px >> OW_sh, ow = px & (OW - 1);
        bq8[i] = q * 8;
        bpx[i] = inb + ((size_t)(oh * S) * IWp + ow * S) * IC;
    }

    f32x4 acc[MF][NF] = {};

    auto STAGE = [&](int buf, int kb) {
        #pragma unroll
        for (int i = 0; i < AISS; ++i)
            gload16(agp[i] + kb, &Ab[buf][(size_t)(i * 512 + t) * 8]);
        const int tap = kb >> IC_sh;
        const int ky = (tap * 11) >> 5, kx = tap - 3 * ky;
        const size_t toff = ((size_t)(ky * IWp + kx) << IC_sh) + (kb & (IC - 1));
        #pragma unroll
        for (int i = 0; i < BISS; ++i)
            gload16(bpx[i] + toff + bq8[i], &Bb[buf][(size_t)(i * 512 + t) * 8]);
    };

    STAGE(0, 0);
    int cur = 0;

    for (int ks = 0; ks < nt; ++ks) {
        if (ks + 1 < nt) {
            STAGE(cur ^ 1, (ks + 1) * 64);
            wait_vm<NSTG>();                // retire current step's loads only
        } else {
            wait_vm<0>();
        }
        bar_mem();                          // buf[cur] ready for all waves

        #pragma unroll
        for (int kk = 0; kk < 2; ++kk) {
            bf16x8 af[MF], bf_[NF];
            #pragma unroll
            for (int m = 0; m < MF; ++m)
                af[m] = ldb8(&Ab[cur][(size_t)((kk * 4 + lg) * BM + wm * (MF * 16) + m * 16 + lr) * 8]);
            #pragma unroll
            for (int n = 0; n < NF; ++n)
                bf_[n] = ldb8(&Bb[cur][(size_t)((kk * 4 + lg) * BN + wn * (NF * 16) + n * 16 + lr) * 8]);
            __builtin_amdgcn_s_setprio(1);
            #pragma unroll
            for (int m = 0; m < MF; ++m)
                #pragma unroll
                for (int n = 0; n < NF; ++n)
                    acc[m][n] = __builtin_amdgcn_mfma_f32_16x16x32_bf16(af[m], bf_[n], acc[m][n], 0, 0, 0);
            __builtin_amdgcn_s_setprio(0);
        }

        bar_mem();                          // all reads of cur done
        cur ^= 1;
    }

    #pragma unroll
    for (int m = 0; m < MF; ++m) {
        const int oc0 = ocb + wm * (MF * 16) + m * 16 + lg * 4;
        const float b0 = bias[oc0], b1 = bias[oc0 + 1], b2 = bias[oc0 + 2], b3 = bias[oc0 + 3];
        #pragma unroll
        for (int n = 0; n < NF; ++n) {
            const int px = pxb + wn * (NF * 16) + n * 16 + lr;
            const int oh = px >> OW_sh, ow = px & (OW - 1);
            const f32x4 a = acc[m][n];
            float v0 = a[0] + b0, v1 = a[1] + b1, v2 = a[2] + b2, v3 = a[3] + b3;
            if (relu) {
                v0 = fmaxf(v0, 0.f); v1 = fmaxf(v1, 0.f);
                v2 = fmaxf(v2, 0.f); v3 = fmaxf(v3, 0.f);
            }
            u32x2 pk;
            pk[0] = (unsigned)f2bf(v0) | ((unsigned)f2bf(v1) << 16);
            pk[1] = (unsigned)f2bf(v2) | ((unsigned)f2bf(v3) << 16);
            u16* op = out + (size_t)b * outSS +
                      (((size_t)(oh + pad_o)) * OWp_o + (ow + pad_o)) * (size_t)OCtot + oc0;
            *(u32x2*)op = pk;
        }
    }
}

// ---- convg3: 4-buffer 3-deep pipeline, CP-parameterized (mergeable) --------
template<int BM, int BN, int NWM, int NWN, int S>
__global__ __launch_bounds__(256, 2)
void convg3_k(CP A, CP B, int split,
              const u16* __restrict__ Wp, const float* __restrict__ bias,
              int IC_sh, int pad_o, int Kreal, int nt, int Kpad, int relu, int OCtot)
{
    constexpr int MF = BM / (NWM * 16);
    constexpr int NF = BN / (NWN * 16);
    constexpr int ASLOT = BM * 4;
    constexpr int BSLOT = BN * 4;
    constexpr int AISS = ASLOT / 256;
    constexpr int BISS = BSLOT / 256;
    constexpr int NSTG = AISS + BISS;

    __shared__ __align__(16) u16 Ab[4][ASLOT * 8];
    __shared__ __align__(16) u16 Bb[4][BSLOT * 8];

    CP P; int bid;
    if (blockIdx.x < (unsigned)split) { P = A; bid = blockIdx.x; }
    else                              { P = B; bid = blockIdx.x - split; }

    const int t    = threadIdx.x;
    const int wv   = t >> 6, lane = t & 63;
    const int lr   = lane & 15, lg = lane >> 4;
    const int wm   = wv / NWN, wn = wv % NWN;

    const int tilesPerB = (OCtot / BM) * P.npt;
    const int b  = bid / tilesPerB;
    const int r0 = bid - b * tilesPerB;
    const int mt = r0 / P.npt, pt = r0 - mt * P.npt;
    const int ocb = mt * BM, pxb = pt * BN;
    const int IC = 1 << IC_sh;
    const int OW = 1 << P.OWsh;

    const u16* __restrict__ inb = P.in + (size_t)b * P.inSS;

    const u16* agp[AISS];
    #pragma unroll
    for (int i = 0; i < AISS; ++i) {
        const int s = i * 256 + t;
        const int q = s / BM, rr = s - q * BM;
        agp[i] = Wp + (size_t)(ocb + rr) * Kpad + q * 8;
    }
    int bq[BISS]; const u16* bpx[BISS];
    #pragma unroll
    for (int i = 0; i < BISS; ++i) {
        const int s = i * 256 + t;
        const int q = s / BN, rr = s - q * BN;
        const int px = pxb + rr;
        const int oh = px >> P.OWsh, ow = px & (OW - 1);
        bq[i] = q;
        bpx[i] = inb + ((size_t)(oh * S) * P.IWp + ow * S) * IC;
    }

    f32x4 acc[MF][NF] = {};

    auto STAGE = [&](int buf, int kb) {
        #pragma unroll
        for (int i = 0; i < AISS; ++i)
            gload16(agp[i] + kb, &Ab[buf][(size_t)(i * 256 + wv * 64) * 8]);
        #pragma unroll
        for (int i = 0; i < BISS; ++i) {
            const int k = kb + bq[i] * 8;
            const int tap = k >> IC_sh;
            const int ic = k & (IC - 1);
            const int ky = (tap * 11) >> 5, kx = tap - 3 * ky;
            const u16* g = bpx[i] + ((size_t)ky * P.IWp + kx) * IC + ic;
            if (k >= Kreal) g = inb;           // zero weights there; any in-bounds addr
            gload16(g, &Bb[buf][(size_t)(i * 256 + wv * 64) * 8]);
        }
    };

    STAGE(0, 0);
    if (1 < nt) STAGE(1, 32);
    if (2 < nt) STAGE(2, 64);

    for (int ks = 0; ks < nt; ++ks) {
        const int rem = nt - 1 - ks;
        if (rem >= 2)      wait_vm<2 * NSTG>();
        else if (rem == 1) wait_vm<NSTG>();
        else               wait_vm<0>();
        bar_mem();
        if (ks + 3 < nt) STAGE((ks + 3) & 3, (ks + 3) * 32);

        const int cur = ks & 3;
        bf16x8 af[MF], bf_[NF];
        #pragma unroll
        for (int m = 0; m < MF; ++m)
            af[m] = ldb8(&Ab[cur][(size_t)(lg * BM + wm * (MF * 16) + m * 16 + lr) * 8]);
        #pragma unroll
        for (int n = 0; n < NF; ++n)
            bf_[n] = ldb8(&Bb[cur][(size_t)(lg * BN + wn * (NF * 16) + n * 16 + lr) * 8]);

        __builtin_amdgcn_s_setprio(1);
        #pragma unroll
        for (int m = 0; m < MF; ++m)
            #pragma unroll
            for (int n = 0; n < NF; ++n)
                acc[m][n] = __builtin_amdgcn_mfma_f32_16x16x32_bf16(af[m], bf_[n], acc[m][n], 0, 0, 0);
        __builtin_amdgcn_s_setprio(0);
    }

    #pragma unroll
    for (int m = 0; m < MF; ++m) {
        const int oc0 = ocb + wm * (MF * 16) + m * 16 + lg * 4;
        const float b0 = bias[oc0], b1 = bias[oc0 + 1], b2 = bias[oc0 + 2], b3 = bias[oc0 + 3];
        #pragma unroll
        for (int n = 0; n < NF; ++n) {
            const int px = pxb + wn * (NF * 16) + n * 16 + lr;
            const int oh = px >> P.OWsh, ow = px & (OW - 1);
            const f32x4 a = acc[m][n];
            float v0 = a[0] + b0, v1 = a[1] + b1, v2 = a[2] + b2, v3 = a[3] + b3;
            if (relu) {
                v0 = fmaxf(v0, 0.f); v1 = fmaxf(v1, 0.f);
                v2 = fmaxf(v2, 0.f); v3 = fmaxf(v3, 0.f);
            }
            u32x2 pk;
            pk[0] = (unsigned)f2bf(v0) | ((unsigned)f2bf(v1) << 16);
            pk[1] = (unsigned)f2bf(v2) | ((unsigned)f2bf(v3) << 16);
            u16* op = P.out + (size_t)b * P.outSS +
                      (((size_t)(oh + pad_o)) * P.OWpo + (ow + pad_o)) * (size_t)OCtot + oc0;
            *(u32x2*)op = pk;
        }
    }
}

// ---- xcorr as batched MFMA GEMM --------------------------------------------
__global__ __launch_bounds__(256)
void xcmf_k(const u16* __restrict__ ffm, const u16* __restrict__ cfm,
            float* __restrict__ R)
{
    const int w    = blockIdx.x * 4 + (threadIdx.x >> 6);   // 1600 waves
    const int lane = threadIdx.x & 63;
    const int lr   = lane & 15, lg = lane >> 4;
    const int b  = w / 25;
    const int tp = w - b * 25;

    const int col0 = tp * 32 + lr;
    const int col1 = col0 + 16;
    const int y0 = col0 / 25, x0 = col0 - y0 * 25;
    const int y1 = col1 / 25, x1 = col1 - y1 * 25;

    const u16* fb = ffm + (size_t)b * 262144;
    const u16* f0 = fb + ((size_t)y0 * 32 + x0) * 256 + lg * 8;
    const u16* f1 = fb + ((size_t)y1 * 32 + x1) * 256 + lg * 8;
    const u16* ab = cfm + (size_t)b * 16384 + (size_t)lr * 2048 + lg * 8;
    const bool arow = (lr < 8);

    f32x4 acc0 = {}, acc1 = {};
    #pragma unroll 4
    for (int kb = 0; kb < 2048; kb += 32) {
        const bf16x8 av = arow ? ldb8(ab + kb) : zerob8();
        const bf16x8 bv0 = ldb8(f0 + kb);
        const bf16x8 bv1 = ldb8(f1 + kb);
        acc0 = __builtin_amdgcn_mfma_f32_16x16x32_bf16(av, bv0, acc0, 0, 0, 0);
        acc1 = __builtin_amdgcn_mfma_f32_16x16x32_bf16(av, bv1, acc1, 0, 0, 0);
    }

    if (lg < 2) {
        float* rb = R + (size_t)b * 6400;
        #pragma unroll
        for (int j = 0; j < 4; ++j) {
            const int d = lg * 4 + j;
            rb[(size_t)d * 800 + col0] = acc0[j];
            rb[(size_t)d * 800 + col1] = acc1[j];
        }
    }
}

// ---- diagonal-band reduce --------------------------------------------------
__global__ __launch_bounds__(256)
void xred_k(const float* __restrict__ R, float* __restrict__ part)
{
    const int i = blockIdx.x * 256 + threadIdx.x;
    if (i >= 40000) return;
    const int b = i / 625;
    const int o = i - b * 625;
    const float* rb = R + (size_t)b * 6400 + o;
    float v = 0.f;
    #pragma unroll
    for (int d = 0; d < 8; ++d) v += rb[(size_t)d * 800 + d * 25];
    part[i] = v;
}

// ---- BatchNorm over all 40000 elements -------------------------------------
__global__ __launch_bounds__(1024)
void bn_k(const float* __restrict__ rmap, const float* __restrict__ gamma,
          const float* __restrict__ beta, float* __restrict__ out)
{
    const int N = 40000;
    const int tid = threadIdx.x;
    __shared__ float rs[1024], rq[1024];
    __shared__ float mean_s, inv_s;
    float s = 0.f, q = 0.f;
    for (int i = tid; i < N; i += 1024) {
        const float v = rmap[i];
        s += v; q += v * v;
    }
    rs[tid] = s; rq[tid] = q;
    __syncthreads();
    for (int off = 512; off > 0; off >>= 1) {
        if (tid < off) { rs[tid] += rs[tid + off]; rq[tid] += rq[tid + off]; }
        __syncthreads();
    }
    if (tid == 0) {
        const float m = rs[0] / (float)N;
        mean_s = m;
        inv_s = rsqrtf(rq[0] / (float)N - m * m + 1e-5f);
    }
    __syncthreads();
    const float g = gamma[0], bt = beta[0];
    for (int i = tid; i < N; i += 1024)
        out[i] = (rmap[i] - mean_s) * inv_s * g + bt;
}

// ---------------------------------------------------------------------------

extern "C" void kernel_launch(void* const* d_in, const int* in_sizes, int n_in,
                              void* d_out, int out_size, void* d_ws, size_t ws_size,
                              hipStream_t stream)
{
    (void)in_sizes; (void)n_in; (void)out_size; (void)ws_size;
    const float* crop  = (const float*)d_in[0];
    const float* frame = (const float*)d_in[1];
    const float* W[5]; const float* bb[5];
    for (int i = 0; i < 5; ++i) { W[i] = (const float*)d_in[2 + 2*i]; bb[i] = (const float*)d_in[3 + 2*i]; }
    const float* gamma = (const float*)d_in[12];
    const float* beta  = (const float*)d_in[13];
    float* out = (float*)d_out;

    unsigned char* ws = (unsigned char*)d_ws;
    // frame pipeline (sizes in BYTES):
    u16*   f0b  = (u16*)(ws + 0);             // [64][130][130][4]   8,652,800 B (dead after fL1)
    u16*   f1p  = (u16*)(ws + 8652800);       // [64][66][66][16]    8,921,088 B (dead after fL2)
    u16*   f2p  = (u16*)(ws + 17573888);      // [64][66][66][64]   35,684,352 B (dead after fL3)
    u16*   f3p  = (u16*)(ws + 53258240);      // [64][34][34][128]  18,939,904 B
    u16*   ffm  = (u16*)(ws + 0);             // [64][32][32][256]  33,554,432 B (aliases dead f0b..f2p)
    // crop pipeline + weights + xcorr after f3p (ends 72,198,144):
    u16*   c0b  = (u16*)(ws + 72198144);      // [64][34][34][4]       591,872 B
    u16*   c1p  = (u16*)(ws + 72790016);      // [64][18][18][16]      663,552 B
    u16*   c2p  = (u16*)(ws + 73453568);      // [64][18][18][64]    2,654,208 B
    u16*   c3p  = (u16*)(ws + 76107776);      // [64][10][10][128]   1,638,400 B
    u16*   cfm  = (u16*)(ws + 77746176);      // [64][8][8][256]     2,097,152 B
    u16*   Wc1  = (u16*)(ws + 79843328);      // [16][64]                2,048 B
    u16*   Wp2  = (u16*)(ws + 79845376);      // [64][160]              20,480 B
    u16*   Wp3  = (u16*)(ws + 79865856);      // [128][576]            147,456 B
    u16*   Wp4  = (u16*)(ws + 80013312);      // [256][1152]           589,824 B
    float* Rbuf = (float*)(ws + 80603136);    // [64][8][800] f32    1,638,400 B
    float* part = (float*)(ws + 82241536);    // [40000] f32           160,000 B

    // ---- one merged halo-zero launch ----
    HZall hz;
    const unsigned long long ptrs[8] = {(unsigned long long)c0b, (unsigned long long)c1p,
        (unsigned long long)c2p, (unsigned long long)c3p, (unsigned long long)f0b,
        (unsigned long long)f1p, (unsigned long long)f2p, (unsigned long long)f3p};
    const int Hps[8] = {34, 18, 18, 10, 130, 66, 66, 34};
    const int w8s[8] = {1, 4, 16, 32, 1, 4, 16, 32};
    int cum = 0;
    for (int i = 0; i < 8; ++i) {
        hz.d[i].ptr = ptrs[i]; hz.d[i].B = 64; hz.d[i].Hp = Hps[i];
        hz.d[i].Wpx = Hps[i]; hz.d[i].w8 = w8s[i]; hz.d[i].cum = cum;
        cum += 64 * (2 * Hps[i] + 2 * (Hps[i] - 2)) * w8s[i];
    }
    hz.total = cum;
    haloz_k<<<1024, 256, 0, stream>>>(hz);

    // ---- one merged weight-pack launch ----
    packall_k<<<1484, 256, 0, stream>>>(W[1], W[2], W[3], W[4], Wc1, Wp2, Wp3, Wp4);

    // ---- merged heads (crop+frame): L0, L1, L2 ----
    conv0m_k<<<1088, 256, 0, stream>>>(crop, frame, W[0], bb[0], c0b, f0b);
    conv1m_k<<<1088, 256, 0, stream>>>(c0b, c1p, f0b, f1p, Wc1, bb[1]);
    {
        CP Ac = {c1p, c2p, 18,  5184, 4, 18, 20736,  1};
        CP Bf = {f1p, f2p, 66, 69696, 6, 66, 278784, 16};
        convg3_k<64,256,1,4,1><<<1088, 256, 0, stream>>>(Ac, Bf, 64, Wp2, bb[2],
            4, 1, 144, 5, 160, 1, 64);
    }

    // ---- crop L3, L4 (small, convg3) ----
    {
        CP A3 = {c2p, c3p, 18, 20736, 3, 10, 12800, 1};
        convg3_k<128,64,4,1,2><<<64, 256, 0, stream>>>(A3, A3, 1 << 30, Wp3, bb[3],
            6, 1, 576, 18, 576, 1, 128);
        CP A4 = {c3p, cfm, 10, 12800, 3, 8, 16384, 1};
        convg3_k<256,64,4,1,1><<<64, 256, 0, stream>>>(A4, A4, 1 << 30, Wp4, bb[4],
            7, 0, 1152, 36, 1152, 0, 256);
    }

    // ---- frame L3, L4 (convh 128x128, 2 blocks/CU) ----
    //       inP  Wp   bias  out  ICsh IWp inSS    OWsh OWpo outSS  pad nt Kpad relu npt OCtot
    convh_k<128,128,2,4,2><<< 512, 512, 0, stream>>>(f2p, Wp3, bb[3], f3p, 6, 66, 278784, 5, 34, 147968, 1,  9,  576, 1, 8, 128);
    convh_k<128,128,2,4,1><<<1024, 512, 0, stream>>>(f3p, Wp4, bb[4], ffm, 7, 34, 147968, 5, 32, 262144, 0, 18, 1152, 0, 8, 256);

    // ---- xcorr (MFMA) + band-reduce + BN ----
    xcmf_k<<<400, 256, 0, stream>>>(ffm, cfm, Rbuf);
    xred_k<<<157, 256, 0, stream>>>(Rbuf, part);
    bn_k<<<1, 1024, 0, stream>>>(part, gamma, beta, out);
}

// Round 10
// 300.280 us; speedup vs baseline: 1.0761x; 1.0461x over previous
//
#include <hip/hip_runtime.h>

// ---------------------------------------------------------------------------
// CorrelationalDetector R10:
//  convp_k: 4-phase-per-K-tile interleaved schedule (m201-style T3+T4) for
//  fL3/fL4. Per phase: {issue one staging piece of tile k+1 | counted
//  vmcnt(WST) at phases 0/2 only (never 0 in steady state) | barrier |
//  ds_read quadrant | MFMA cluster | barrier}. Issue->wait distance ~4 phases.
//  Race-freedom: piece p of buffer X is written while the only possible
//  laggard readers of X touch the complementary k-oct range (disjoint), and
//  wave skew is <=1 barrier.
//  fL4 keeps R8's best geometry (256x256, wave-tile 128x64, 1 blk/CU).
//  Heads (merged), crop convg3, xcorr, BN unchanged from R9.
// ---------------------------------------------------------------------------

typedef __bf16 bf16x8 __attribute__((ext_vector_type(8)));
typedef float f32x4 __attribute__((ext_vector_type(4)));
typedef unsigned int u32x4 __attribute__((ext_vector_type(4)));
typedef unsigned int u32x2 __attribute__((ext_vector_type(2)));
typedef unsigned short u16;

#define AS1 __attribute__((address_space(1)))
#define AS3 __attribute__((address_space(3)))

__device__ __forceinline__ u16 f2bf(float v) {
    unsigned u = __float_as_uint(v);
    u += 0x7fffu + ((u >> 16) & 1u);          // RNE
    return (u16)(u >> 16);
}

__device__ __forceinline__ bf16x8 ldb8(const u16* p) {
    return *(const bf16x8*)p;
}

__device__ __forceinline__ bf16x8 zerob8() {
    u32x4 z = {0u, 0u, 0u, 0u};
    bf16x8 r;
    __builtin_memcpy(&r, &z, 16);
    return r;
}

__device__ __forceinline__ void gload16(const u16* g, u16* l) {
    __builtin_amdgcn_global_load_lds((const AS1 void*)g, (AS3 void*)l, 16, 0, 0);
}

template<int N> __device__ __forceinline__ void wait_vm() {
    asm volatile("s_waitcnt vmcnt(%0)" :: "i"(N) : "memory");
}

__device__ __forceinline__ void bar_mem() {
    asm volatile("" ::: "memory");
    __builtin_amdgcn_s_barrier();
    asm volatile("" ::: "memory");
}

// per-side geometry for merged / CP-parameterized conv kernels
struct CP { const u16* in; u16* out; int IWp, inSS, OWsh, OWpo, outSS, npt; };

// ---- merged halo zero ------------------------------------------------------
struct HZd { unsigned long long ptr; int B, Hp, Wpx, w8, cum; };
struct HZall { HZd d[8]; int total; };

__global__ __launch_bounds__(256)
void haloz_k(HZall h)
{
    for (int i = blockIdx.x * 256 + threadIdx.x; i < h.total; i += gridDim.x * 256) {
        int di = 0;
        #pragma unroll
        for (int j = 1; j < 8; ++j) if (i >= h.d[j].cum) di = j;
        const HZd D = h.d[di];
        const int loc = i - D.cum;
        const int w = loc % D.w8; int t2 = loc / D.w8;
        const int bord = 2 * D.Wpx + 2 * (D.Hp - 2);
        const int pb = t2 % bord; const int b = t2 / bord;
        int oh, ow;
        if (pb < D.Wpx)            { oh = 0;        ow = pb; }
        else if (pb < 2 * D.Wpx)   { oh = D.Hp - 1; ow = pb - D.Wpx; }
        else { const int q = pb - 2 * D.Wpx; oh = 1 + (q >> 1); ow = (q & 1) ? (D.Wpx - 1) : 0; }
        ((unsigned long long*)D.ptr)[((size_t)b * D.Hp * D.Wpx + (size_t)oh * D.Wpx + ow) * D.w8 + w] = 0ull;
    }
}

// ---- merged weight pack ----------------------------------------------------
__device__ __forceinline__ void packone(const float* W, u16* Wp, int idx,
                                        int ICsh, int Kpad)
{
    const int k = idx % Kpad, oc = idx / Kpad;
    const int tap = k >> ICsh, ic = k & ((1 << ICsh) - 1);
    const float v = (tap < 9) ? W[((size_t)(oc << ICsh) + ic) * 9 + tap] : 0.f;
    Wp[idx] = f2bf(v);
}

__global__ __launch_bounds__(256)
void packall_k(const float* __restrict__ W1, const float* __restrict__ W2,
               const float* __restrict__ W3, const float* __restrict__ W4,
               u16* __restrict__ Wc1, u16* __restrict__ Wp2,
               u16* __restrict__ Wp3, u16* __restrict__ Wp4)
{
    const int i = blockIdx.x * 256 + threadIdx.x;
    if (i < 1024) {                       // Wc1: [16][64], k = ky*16+kx*4+ic
        const int k = i & 63, oc = i >> 6;
        const int ky = k >> 4, kx = (k >> 2) & 3, ic = k & 3;
        const float v = (ky < 3 && kx < 3 && ic < 3) ? W1[oc * 27 + ic * 9 + ky * 3 + kx] : 0.f;
        Wc1[i] = f2bf(v);
    } else if (i < 11264) {               // 1024 + 64*160
        packone(W2, Wp2, i - 1024, 4, 160);
    } else if (i < 84992) {               // + 128*576
        packone(W3, Wp3, i - 11264, 6, 576);
    } else if (i < 379904) {              // + 256*1152
        packone(W4, Wp4, i - 84992, 7, 1152);
    }
}

// ---- L0 body ----------------------------------------------------------------
__device__ __forceinline__ void conv0_body(const float* __restrict__ in,
                                           const float* __restrict__ W,
                                           const float* __restrict__ bias,
                                           u16* __restrict__ outP,
                                           int IH, int IW, int OH, int OW, int idx)
{
    const int OW4 = OW >> 2;
    const int OWp = OW + 2, OHp = OH + 2;
    const int ow4 = idx % OW4; int t = idx / OW4;
    const int oh = t % OH;  const int b = t / OH;
    const int owb = ow4 * 4;
    float a0[4], a1[4], a2[4];
    #pragma unroll
    for (int j = 0; j < 4; ++j) { a0[j] = bias[0]; a1[j] = bias[1]; a2[j] = bias[2]; }
    const float* inb = in + (size_t)b * 3 * IH * IW;
    const int xbase = owb * 2 - 1;
    #pragma unroll
    for (int ic = 0; ic < 3; ++ic) {
        const float* ip = inb + (size_t)ic * IH * IW;
        #pragma unroll
        for (int ky = 0; ky < 3; ++ky) {
            const int y = oh * 2 - 1 + ky;
            if ((unsigned)y >= (unsigned)IH) continue;
            const float* rp = ip + (size_t)y * IW;
            float xr[9];
            #pragma unroll
            for (int i2 = 0; i2 < 9; ++i2) {
                const int x = xbase + i2;
                xr[i2] = ((unsigned)x < (unsigned)IW) ? rp[x] : 0.f;
            }
            #pragma unroll
            for (int kx = 0; kx < 3; ++kx) {
                const float w0 = W[0 * 27 + ic * 9 + ky * 3 + kx];
                const float w1 = W[1 * 27 + ic * 9 + ky * 3 + kx];
                const float w2 = W[2 * 27 + ic * 9 + ky * 3 + kx];
                #pragma unroll
                for (int j = 0; j < 4; ++j) {
                    const float xv = xr[2 * j + kx];
                    a0[j] += xv * w0; a1[j] += xv * w1; a2[j] += xv * w2;
                }
            }
        }
    }
    u16* op = outP + (((size_t)b * OHp + oh + 1) * OWp + owb + 1) * 4;
    #pragma unroll
    for (int j = 0; j < 4; ++j) {
        u32x2 pk;
        pk[0] = (unsigned)f2bf(fmaxf(a0[j], 0.f)) | ((unsigned)f2bf(fmaxf(a1[j], 0.f)) << 16);
        pk[1] = (unsigned)f2bf(fmaxf(a2[j], 0.f));
        *(u32x2*)(op + j * 4) = pk;
    }
}

__global__ __launch_bounds__(256)
void conv0m_k(const float* __restrict__ crop, const float* __restrict__ frame,
              const float* __restrict__ W, const float* __restrict__ bias,
              u16* __restrict__ c0b, u16* __restrict__ f0b)
{
    if (blockIdx.x < 64)
        conv0_body(crop, W, bias, c0b, 64, 64, 32, 32, blockIdx.x * 256 + threadIdx.x);
    else
        conv0_body(frame, W, bias, f0b, 256, 256, 128, 128, (blockIdx.x - 64) * 256 + threadIdx.x);
}

// ---- L1 body: MFMA GEMM M=16 oc, K=64 --------------------------------------
__device__ __forceinline__ void conv1g_body(const u16* __restrict__ inP,
                                            const u16* __restrict__ Wc1,
                                            const float* __restrict__ bias,
                                            u16* __restrict__ outP,
                                            int IWp, int inSS, int OWp, int outSS,
                                            int OWsh, int HWsh, int w, int lane)
{
    const int lr = lane & 15, lg = lane >> 4;
    const int pxb = w * 64;
    const int OW = 1 << OWsh;

    const bf16x8 av0 = ldb8(Wc1 + lr * 64 + lg * 8);
    const bf16x8 av1 = ldb8(Wc1 + lr * 64 + 32 + lg * 8);
    const int ky0 = lg >> 1, kxb = (lg & 1) * 2;
    const int ky1 = 2 + (lg >> 1);

    f32x4 acc[4] = {};
    #pragma unroll
    for (int n = 0; n < 4; ++n) {
        const int px = pxb + n * 16 + lr;
        const int b = px >> HWsh;
        const int rem = px & ((1 << HWsh) - 1);
        const int oh = rem >> OWsh, ow = rem & (OW - 1);
        const u16* ib = inP + (size_t)b * inSS + (((size_t)(oh * 2)) * IWp + ow * 2) * 4;
        const bf16x8 bv0 = ldb8(ib + ((size_t)ky0 * IWp + kxb) * 4);
        acc[n] = __builtin_amdgcn_mfma_f32_16x16x32_bf16(av0, bv0, acc[n], 0, 0, 0);
        const bf16x8 bv1 = ldb8(ib + ((size_t)ky1 * IWp + kxb) * 4);
        acc[n] = __builtin_amdgcn_mfma_f32_16x16x32_bf16(av1, bv1, acc[n], 0, 0, 0);
    }

    const float b0 = bias[lg * 4], b1 = bias[lg * 4 + 1],
                b2 = bias[lg * 4 + 2], b3 = bias[lg * 4 + 3];
    #pragma unroll
    for (int n = 0; n < 4; ++n) {
        const int px = pxb + n * 16 + lr;
        const int b = px >> HWsh;
        const int rem = px & ((1 << HWsh) - 1);
        const int oh = rem >> OWsh, ow = rem & (OW - 1);
        const f32x4 a = acc[n];
        u32x2 pk;
        pk[0] = (unsigned)f2bf(fmaxf(a[0] + b0, 0.f)) | ((unsigned)f2bf(fmaxf(a[1] + b1, 0.f)) << 16);
        pk[1] = (unsigned)f2bf(fmaxf(a[2] + b2, 0.f)) | ((unsigned)f2bf(fmaxf(a[3] + b3, 0.f)) << 16);
        u16* op = outP + (size_t)b * outSS + (((size_t)(oh + 1)) * OWp + (ow + 1)) * 16 + lg * 4;
        *(u32x2*)op = pk;
    }
}

__global__ __launch_bounds__(256)
void conv1m_k(const u16* __restrict__ c0b, u16* __restrict__ c1p,
              const u16* __restrict__ f0b, u16* __restrict__ f1p,
              const u16* __restrict__ Wc1, const float* __restrict__ bias)
{
    const int wv = threadIdx.x >> 6, lane = threadIdx.x & 63;
    if (blockIdx.x < 64)
        conv1g_body(c0b, Wc1, bias, c1p, 34, 4624, 18, 5184, 4, 8, blockIdx.x * 4 + wv, lane);
    else
        conv1g_body(f0b, Wc1, bias, f1p, 130, 67600, 66, 69696, 6, 12, (blockIdx.x - 64) * 4 + wv, lane);
}

// ---- convp: 4-phase-per-K-tile interleaved MFMA conv GEMM ------------------
// Requires: BK=64 <= IC (tap uniform per K-step), Kpad = 9*IC, MF even.
// Phases p=(kk,mh): p0(k0,m0) p1(k0,m1) p2(k1,m0) p3(k1,m1).
// Staging pieces of tile ks+1 issued: p0->A-half0, p1->B-half0, p2->A-half1,
// p3->B-half1 (piece h covers k-octs of kk-half h only -> disjoint from any
// laggard reader of the same buffer). vmcnt(WST) at p0/p2; WST = LT/2 + AH.
template<int BM, int BN, int NWM, int NWN, int S>
__global__ __launch_bounds__(512, 2)
void convp_k(const u16* __restrict__ inP, const u16* __restrict__ Wp,
             const float* __restrict__ bias, u16* __restrict__ out,
             int IC_sh, int IWp, int inSS, int OW_sh, int OWp_o, int outSS,
             int pad_o, int nt, int Kpad, int relu, int n_pt, int OCtot)
{
    constexpr int MF = BM / (NWM * 16);
    constexpr int NF = BN / (NWN * 16);
    constexpr int MH = MF / 2;
    constexpr int ASLOT = BM * 8;          // 16B slots per buffer (BK=64)
    constexpr int BSLOT = BN * 8;
    constexpr int AISS = ASLOT / 512;      // per-thread A loads per tile
    constexpr int BISS = BSLOT / 512;
    constexpr int AH = AISS / 2, BH = BISS / 2;
    constexpr int LT = AISS + BISS;
    constexpr int WST = LT / 2 + AH;       // steady-state counted vmcnt

    __shared__ __align__(16) u16 Ab[2][ASLOT * 8];
    __shared__ __align__(16) u16 Bb[2][BSLOT * 8];

    const int t    = threadIdx.x;
    const int wv   = t >> 6, lane = t & 63;
    const int lr   = lane & 15, lg = lane >> 4;
    const int wm   = wv / NWN, wn = wv % NWN;

    const int tilesPerB = (OCtot / BM) * n_pt;
    const int b  = blockIdx.x / tilesPerB;
    const int r0 = blockIdx.x - b * tilesPerB;
    const int mt = r0 / n_pt, pt = r0 - mt * n_pt;
    const int ocb = mt * BM, pxb = pt * BN;
    const int IC = 1 << IC_sh;
    const int OW = 1 << OW_sh;

    const u16* __restrict__ inb = inP + (size_t)b * inSS;

    const u16* agp[AISS];
    #pragma unroll
    for (int i = 0; i < AISS; ++i) {
        const int s = i * 512 + t;
        const int q = s / BM, rr = s - q * BM;
        agp[i] = Wp + (size_t)(ocb + rr) * Kpad + q * 8;
    }
    int bq8[BISS]; const u16* bpx[BISS];
    #pragma unroll
    for (int i = 0; i < BISS; ++i) {
        const int s = i * 512 + t;
        const int q = s / BN, rr = s - q * BN;
        const int px = pxb + rr;
        const int oh = px >> OW_sh, ow = px & (OW - 1);
        bq8[i] = q * 8;
        bpx[i] = inb + ((size_t)(oh * S) * IWp + ow * S) * IC;
    }

    f32x4 acc[MF][NF] = {};

    auto STAGE_A = [&](int buf, int kb, int h) {
        #pragma unroll
        for (int i = h * AH; i < (h + 1) * AH; ++i)
            gload16(agp[i] + kb, &Ab[buf][(size_t)(i * 512 + t) * 8]);
    };
    auto STAGE_B = [&](int buf, int kb, int h) {
        const int tap = kb >> IC_sh;          // uniform: BK=64 <= IC
        const int ky = (tap * 11) >> 5, kx = tap - 3 * ky;
        const size_t toff = ((size_t)(ky * IWp + kx) << IC_sh) + (kb & (IC - 1));
        #pragma unroll
        for (int i = h * BH; i < (h + 1) * BH; ++i)
            gload16(bpx[i] + toff + bq8[i], &Bb[buf][(size_t)(i * 512 + t) * 8]);
    };

    // prologue: tile 0, issue order A-h0, B-h0, A-h1, B-h1 (FIFO basis for waits)
    STAGE_A(0, 0, 0); STAGE_B(0, 0, 0); STAGE_A(0, 0, 1); STAGE_B(0, 0, 1);

    for (int ks = 0; ks < nt; ++ks) {
        const int cur = ks & 1, nxt = cur ^ 1;
        const int kb1 = (ks + 1) * 64;
        const bool pf = (ks + 1 < nt);
        bf16x8 bfc[NF], af[MH];

        // ---- p0: kk=0, mh=0 ----
        if (pf) { STAGE_A(nxt, kb1, 0); wait_vm<WST>(); }
        else    { wait_vm<LT / 2>(); }
        bar_mem();                            // A-h0,B-h0 of tile ks visible
        #pragma unroll
        for (int n = 0; n < NF; ++n)
            bfc[n] = ldb8(&Bb[cur][(size_t)(lg * BN + wn * (NF * 16) + n * 16 + lr) * 8]);
        #pragma unroll
        for (int m = 0; m < MH; ++m)
            af[m] = ldb8(&Ab[cur][(size_t)(lg * BM + wm * (MF * 16) + m * 16 + lr) * 8]);
        __builtin_amdgcn_s_setprio(1);
        #pragma unroll
        for (int m = 0; m < MH; ++m)
            #pragma unroll
            for (int n = 0; n < NF; ++n)
                acc[m][n] = __builtin_amdgcn_mfma_f32_16x16x32_bf16(af[m], bfc[n], acc[m][n], 0, 0, 0);
        __builtin_amdgcn_s_setprio(0);
        bar_mem();

        // ---- p1: kk=0, mh=1 (bfc reused) ----
        if (pf) STAGE_B(nxt, kb1, 0);
        #pragma unroll
        for (int m = 0; m < MH; ++m)
            af[m] = ldb8(&Ab[cur][(size_t)(lg * BM + wm * (MF * 16) + (MH + m) * 16 + lr) * 8]);
        __builtin_amdgcn_s_setprio(1);
        #pragma unroll
        for (int m = 0; m < MH; ++m)
            #pragma unroll
            for (int n = 0; n < NF; ++n)
                acc[MH + m][n] = __builtin_amdgcn_mfma_f32_16x16x32_bf16(af[m], bfc[n], acc[MH + m][n], 0, 0, 0);
        __builtin_amdgcn_s_setprio(0);
        bar_mem();

        // ---- p2: kk=1, mh=0 ----
        if (pf) { STAGE_A(nxt, kb1, 1); wait_vm<WST>(); }
        else    { wait_vm<0>(); }
        bar_mem();                            // A-h1,B-h1 of tile ks visible
        #pragma unroll
        for (int n = 0; n < NF; ++n)
            bfc[n] = ldb8(&Bb[cur][(size_t)((4 + lg) * BN + wn * (NF * 16) + n * 16 + lr) * 8]);
        #pragma unroll
        for (int m = 0; m < MH; ++m)
            af[m] = ldb8(&Ab[cur][(size_t)((4 + lg) * BM + wm * (MF * 16) + m * 16 + lr) * 8]);
        __builtin_amdgcn_s_setprio(1);
        #pragma unroll
        for (int m = 0; m < MH; ++m)
            #pragma unroll
            for (int n = 0; n < NF; ++n)
                acc[m][n] = __builtin_amdgcn_mfma_f32_16x16x32_bf16(af[m], bfc[n], acc[m][n], 0, 0, 0);
        __builtin_amdgcn_s_setprio(0);
        bar_mem();

        // ---- p3: kk=1, mh=1 ----
        if (pf) STAGE_B(nxt, kb1, 1);
        #pragma unroll
        for (int m = 0; m < MH; ++m)
            af[m] = ldb8(&Ab[cur][(size_t)((4 + lg) * BM + wm * (MF * 16) + (MH + m) * 16 + lr) * 8]);
        __builtin_amdgcn_s_setprio(1);
        #pragma unroll
        for (int m = 0; m < MH; ++m)
            #pragma unroll
            for (int n = 0; n < NF; ++n)
                acc[MH + m][n] = __builtin_amdgcn_mfma_f32_16x16x32_bf16(af[m], bfc[n], acc[MH + m][n], 0, 0, 0);
        __builtin_amdgcn_s_setprio(0);
        bar_mem();
    }

    #pragma unroll
    for (int m = 0; m < MF; ++m) {
        const int oc0 = ocb + wm * (MF * 16) + m * 16 + lg * 4;
        const float b0 = bias[oc0], b1 = bias[oc0 + 1], b2 = bias[oc0 + 2], b3 = bias[oc0 + 3];
        #pragma unroll
        for (int n = 0; n < NF; ++n) {
            const int px = pxb + wn * (NF * 16) + n * 16 + lr;
            const int oh = px >> OW_sh, ow = px & (OW - 1);
            const f32x4 a = acc[m][n];
            float v0 = a[0] + b0, v1 = a[1] + b1, v2 = a[2] + b2, v3 = a[3] + b3;
            if (relu) {
                v0 = fmaxf(v0, 0.f); v1 = fmaxf(v1, 0.f);
                v2 = fmaxf(v2, 0.f); v3 = fmaxf(v3, 0.f);
            }
            u32x2 pk;
            pk[0] = (unsigned)f2bf(v0) | ((unsigned)f2bf(v1) << 16);
            pk[1] = (unsigned)f2bf(v2) | ((unsigned)f2bf(v3) << 16);
            u16* op = out + (size_t)b * outSS +
                      (((size_t)(oh + pad_o)) * OWp_o + (ow + pad_o)) * (size_t)OCtot + oc0;
            *(u32x2*)op = pk;
        }
    }
}

// ---- convg3: 4-buffer 3-deep pipeline, CP-parameterized --------------------
template<int BM, int BN, int NWM, int NWN, int S>
__global__ __launch_bounds__(256, 2)
void convg3_k(CP A, CP B, int split,
              const u16* __restrict__ Wp, const float* __restrict__ bias,
              int IC_sh, int pad_o, int Kreal, int nt, int Kpad, int relu, int OCtot)
{
    constexpr int MF = BM / (NWM * 16);
    constexpr int NF = BN / (NWN * 16);
    constexpr int ASLOT = BM * 4;
    constexpr int BSLOT = BN * 4;
    constexpr int AISS = ASLOT / 256;
    constexpr int BISS = BSLOT / 256;
    constexpr int NSTG = AISS + BISS;

    __shared__ __align__(16) u16 Ab[4][ASLOT * 8];
    __shared__ __align__(16) u16 Bb[4][BSLOT * 8];

    CP P; int bid;
    if (blockIdx.x < (unsigned)split) { P = A; bid = blockIdx.x; }
    else                              { P = B; bid = blockIdx.x - split; }

    const int t    = threadIdx.x;
    const int wv   = t >> 6, lane = t & 63;
    const int lr   = lane & 15, lg = lane >> 4;
    const int wm   = wv / NWN, wn = wv % NWN;

    const int tilesPerB = (OCtot / BM) * P.npt;
    const int b  = bid / tilesPerB;
    const int r0 = bid - b * tilesPerB;
    const int mt = r0 / P.npt, pt = r0 - mt * P.npt;
    const int ocb = mt * BM, pxb = pt * BN;
    const int IC = 1 << IC_sh;
    const int OW = 1 << P.OWsh;

    const u16* __restrict__ inb = P.in + (size_t)b * P.inSS;

    const u16* agp[AISS];
    #pragma unroll
    for (int i = 0; i < AISS; ++i) {
        const int s = i * 256 + t;
        const int q = s / BM, rr = s - q * BM;
        agp[i] = Wp + (size_t)(ocb + rr) * Kpad + q * 8;
    }
    int bq[BISS]; const u16* bpx[BISS];
    #pragma unroll
    for (int i = 0; i < BISS; ++i) {
        const int s = i * 256 + t;
        const int q = s / BN, rr = s - q * BN;
        const int px = pxb + rr;
        const int oh = px >> P.OWsh, ow = px & (OW - 1);
        bq[i] = q;
        bpx[i] = inb + ((size_t)(oh * S) * P.IWp + ow * S) * IC;
    }

    f32x4 acc[MF][NF] = {};

    auto STAGE = [&](int buf, int kb) {
        #pragma unroll
        for (int i = 0; i < AISS; ++i)
            gload16(agp[i] + kb, &Ab[buf][(size_t)(i * 256 + wv * 64) * 8]);
        #pragma unroll
        for (int i = 0; i < BISS; ++i) {
            const int k = kb + bq[i] * 8;
            const int tap = k >> IC_sh;
            const int ic = k & (IC - 1);
            const int ky = (tap * 11) >> 5, kx = tap - 3 * ky;
            const u16* g = bpx[i] + ((size_t)ky * P.IWp + kx) * IC + ic;
            if (k >= Kreal) g = inb;           // zero weights there; any in-bounds addr
            gload16(g, &Bb[buf][(size_t)(i * 256 + wv * 64) * 8]);
        }
    };

    STAGE(0, 0);
    if (1 < nt) STAGE(1, 32);
    if (2 < nt) STAGE(2, 64);

    for (int ks = 0; ks < nt; ++ks) {
        const int rem = nt - 1 - ks;
        if (rem >= 2)      wait_vm<2 * NSTG>();
        else if (rem == 1) wait_vm<NSTG>();
        else               wait_vm<0>();
        bar_mem();
        if (ks + 3 < nt) STAGE((ks + 3) & 3, (ks + 3) * 32);

        const int cur = ks & 3;
        bf16x8 af[MF], bf_[NF];
        #pragma unroll
        for (int m = 0; m < MF; ++m)
            af[m] = ldb8(&Ab[cur][(size_t)(lg * BM + wm * (MF * 16) + m * 16 + lr) * 8]);
        #pragma unroll
        for (int n = 0; n < NF; ++n)
            bf_[n] = ldb8(&Bb[cur][(size_t)(lg * BN + wn * (NF * 16) + n * 16 + lr) * 8]);

        __builtin_amdgcn_s_setprio(1);
        #pragma unroll
        for (int m = 0; m < MF; ++m)
            #pragma unroll
            for (int n = 0; n < NF; ++n)
                acc[m][n] = __builtin_amdgcn_mfma_f32_16x16x32_bf16(af[m], bf_[n], acc[m][n], 0, 0, 0);
        __builtin_amdgcn_s_setprio(0);
    }

    #pragma unroll
    for (int m = 0; m < MF; ++m) {
        const int oc0 = ocb + wm * (MF * 16) + m * 16 + lg * 4;
        const float b0 = bias[oc0], b1 = bias[oc0 + 1], b2 = bias[oc0 + 2], b3 = bias[oc0 + 3];
        #pragma unroll
        for (int n = 0; n < NF; ++n) {
            const int px = pxb + wn * (NF * 16) + n * 16 + lr;
            const int oh = px >> P.OWsh, ow = px & (OW - 1);
            const f32x4 a = acc[m][n];
            float v0 = a[0] + b0, v1 = a[1] + b1, v2 = a[2] + b2, v3 = a[3] + b3;
            if (relu) {
                v0 = fmaxf(v0, 0.f); v1 = fmaxf(v1, 0.f);
                v2 = fmaxf(v2, 0.f); v3 = fmaxf(v3, 0.f);
            }
            u32x2 pk;
            pk[0] = (unsigned)f2bf(v0) | ((unsigned)f2bf(v1) << 16);
            pk[1] = (unsigned)f2bf(v2) | ((unsigned)f2bf(v3) << 16);
            u16* op = P.out + (size_t)b * P.outSS +
                      (((size_t)(oh + pad_o)) * P.OWpo + (ow + pad_o)) * (size_t)OCtot + oc0;
            *(u32x2*)op = pk;
        }
    }
}

// ---- xcorr as batched MFMA GEMM --------------------------------------------
__global__ __launch_bounds__(256)
void xcmf_k(const u16* __restrict__ ffm, const u16* __restrict__ cfm,
            float* __restrict__ R)
{
    const int w    = blockIdx.x * 4 + (threadIdx.x >> 6);   // 1600 waves
    const int lane = threadIdx.x & 63;
    const int lr   = lane & 15, lg = lane >> 4;
    const int b  = w / 25;
    const int tp = w - b * 25;

    const int col0 = tp * 32 + lr;
    const int col1 = col0 + 16;
    const int y0 = col0 / 25, x0 = col0 - y0 * 25;
    const int y1 = col1 / 25, x1 = col1 - y1 * 25;

    const u16* fb = ffm + (size_t)b * 262144;
    const u16* f0 = fb + ((size_t)y0 * 32 + x0) * 256 + lg * 8;
    const u16* f1 = fb + ((size_t)y1 * 32 + x1) * 256 + lg * 8;
    const u16* ab = cfm + (size_t)b * 16384 + (size_t)lr * 2048 + lg * 8;
    const bool arow = (lr < 8);

    f32x4 acc0 = {}, acc1 = {};
    #pragma unroll 4
    for (int kb = 0; kb < 2048; kb += 32) {
        const bf16x8 av = arow ? ldb8(ab + kb) : zerob8();
        const bf16x8 bv0 = ldb8(f0 + kb);
        const bf16x8 bv1 = ldb8(f1 + kb);
        acc0 = __builtin_amdgcn_mfma_f32_16x16x32_bf16(av, bv0, acc0, 0, 0, 0);
        acc1 = __builtin_amdgcn_mfma_f32_16x16x32_bf16(av, bv1, acc1, 0, 0, 0);
    }

    if (lg < 2) {
        float* rb = R + (size_t)b * 6400;
        #pragma unroll
        for (int j = 0; j < 4; ++j) {
            const int d = lg * 4 + j;
            rb[(size_t)d * 800 + col0] = acc0[j];
            rb[(size_t)d * 800 + col1] = acc1[j];
        }
    }
}

// ---- diagonal-band reduce --------------------------------------------------
__global__ __launch_bounds__(256)
void xred_k(const float* __restrict__ R, float* __restrict__ part)
{
    const int i = blockIdx.x * 256 + threadIdx.x;
    if (i >= 40000) return;
    const int b = i / 625;
    const int o = i - b * 625;
    const float* rb = R + (size_t)b * 6400 + o;
    float v = 0.f;
    #pragma unroll
    for (int d = 0; d < 8; ++d) v += rb[(size_t)d * 800 + d * 25];
    part[i] = v;
}

// ---- BatchNorm over all 40000 elements -------------------------------------
__global__ __launch_bounds__(1024)
void bn_k(const float* __restrict__ rmap, const float* __restrict__ gamma,
          const float* __restrict__ beta, float* __restrict__ out)
{
    const int N = 40000;
    const int tid = threadIdx.x;
    __shared__ float rs[1024], rq[1024];
    __shared__ float mean_s, inv_s;
    float s = 0.f, q = 0.f;
    for (int i = tid; i < N; i += 1024) {
        const float v = rmap[i];
        s += v; q += v * v;
    }
    rs[tid] = s; rq[tid] = q;
    __syncthreads();
    for (int off = 512; off > 0; off >>= 1) {
        if (tid < off) { rs[tid] += rs[tid + off]; rq[tid] += rq[tid + off]; }
        __syncthreads();
    }
    if (tid == 0) {
        const float m = rs[0] / (float)N;
        mean_s = m;
        inv_s = rsqrtf(rq[0] / (float)N - m * m + 1e-5f);
    }
    __syncthreads();
    const float g = gamma[0], bt = beta[0];
    for (int i = tid; i < N; i += 1024)
        out[i] = (rmap[i] - mean_s) * inv_s * g + bt;
}

// ---------------------------------------------------------------------------

extern "C" void kernel_launch(void* const* d_in, const int* in_sizes, int n_in,
                              void* d_out, int out_size, void* d_ws, size_t ws_size,
                              hipStream_t stream)
{
    (void)in_sizes; (void)n_in; (void)out_size; (void)ws_size;
    const float* crop  = (const float*)d_in[0];
    const float* frame = (const float*)d_in[1];
    const float* W[5]; const float* bb[5];
    for (int i = 0; i < 5; ++i) { W[i] = (const float*)d_in[2 + 2*i]; bb[i] = (const float*)d_in[3 + 2*i]; }
    const float* gamma = (const float*)d_in[12];
    const float* beta  = (const float*)d_in[13];
    float* out = (float*)d_out;

    unsigned char* ws = (unsigned char*)d_ws;
    // frame pipeline (sizes in BYTES):
    u16*   f0b  = (u16*)(ws + 0);             // [64][130][130][4]   8,652,800 B (dead after fL1)
    u16*   f1p  = (u16*)(ws + 8652800);       // [64][66][66][16]    8,921,088 B (dead after fL2)
    u16*   f2p  = (u16*)(ws + 17573888);      // [64][66][66][64]   35,684,352 B (dead after fL3)
    u16*   f3p  = (u16*)(ws + 53258240);      // [64][34][34][128]  18,939,904 B
    u16*   ffm  = (u16*)(ws + 0);             // [64][32][32][256]  33,554,432 B (aliases dead f0b..f2p)
    // crop pipeline + weights + xcorr after f3p (ends 72,198,144):
    u16*   c0b  = (u16*)(ws + 72198144);      // [64][34][34][4]       591,872 B
    u16*   c1p  = (u16*)(ws + 72790016);      // [64][18][18][16]      663,552 B
    u16*   c2p  = (u16*)(ws + 73453568);      // [64][18][18][64]    2,654,208 B
    u16*   c3p  = (u16*)(ws + 76107776);      // [64][10][10][128]   1,638,400 B
    u16*   cfm  = (u16*)(ws + 77746176);      // [64][8][8][256]     2,097,152 B
    u16*   Wc1  = (u16*)(ws + 79843328);      // [16][64]                2,048 B
    u16*   Wp2  = (u16*)(ws + 79845376);      // [64][160]              20,480 B
    u16*   Wp3  = (u16*)(ws + 79865856);      // [128][576]            147,456 B
    u16*   Wp4  = (u16*)(ws + 80013312);      // [256][1152]           589,824 B
    float* Rbuf = (float*)(ws + 80603136);    // [64][8][800] f32    1,638,400 B
    float* part = (float*)(ws + 82241536);    // [40000] f32           160,000 B

    // ---- one merged halo-zero launch ----
    HZall hz;
    const unsigned long long ptrs[8] = {(unsigned long long)c0b, (unsigned long long)c1p,
        (unsigned long long)c2p, (unsigned long long)c3p, (unsigned long long)f0b,
        (unsigned long long)f1p, (unsigned long long)f2p, (unsigned long long)f3p};
    const int Hps[8] = {34, 18, 18, 10, 130, 66, 66, 34};
    const int w8s[8] = {1, 4, 16, 32, 1, 4, 16, 32};
    int cum = 0;
    for (int i = 0; i < 8; ++i) {
        hz.d[i].ptr = ptrs[i]; hz.d[i].B = 64; hz.d[i].Hp = Hps[i];
        hz.d[i].Wpx = Hps[i]; hz.d[i].w8 = w8s[i]; hz.d[i].cum = cum;
        cum += 64 * (2 * Hps[i] + 2 * (Hps[i] - 2)) * w8s[i];
    }
    hz.total = cum;
    haloz_k<<<1024, 256, 0, stream>>>(hz);

    // ---- one merged weight-pack launch ----
    packall_k<<<1484, 256, 0, stream>>>(W[1], W[2], W[3], W[4], Wc1, Wp2, Wp3, Wp4);

    // ---- merged heads (crop+frame): L0, L1, L2 ----
    conv0m_k<<<1088, 256, 0, stream>>>(crop, frame, W[0], bb[0], c0b, f0b);
    conv1m_k<<<1088, 256, 0, stream>>>(c0b, c1p, f0b, f1p, Wc1, bb[1]);
    {
        CP Ac = {c1p, c2p, 18,  5184, 4, 18, 20736,  1};
        CP Bf = {f1p, f2p, 66, 69696, 6, 66, 278784, 16};
        convg3_k<64,256,1,4,1><<<1088, 256, 0, stream>>>(Ac, Bf, 64, Wp2, bb[2],
            4, 1, 144, 5, 160, 1, 64);
    }

    // ---- crop L3, L4 (small, convg3) ----
    {
        CP A3 = {c2p, c3p, 18, 20736, 3, 10, 12800, 1};
        convg3_k<128,64,4,1,2><<<64, 256, 0, stream>>>(A3, A3, 1 << 30, Wp3, bb[3],
            6, 1, 576, 18, 576, 1, 128);
        CP A4 = {c3p, cfm, 10, 12800, 3, 8, 16384, 1};
        convg3_k<256,64,4,1,1><<<64, 256, 0, stream>>>(A4, A4, 1 << 30, Wp4, bb[4],
            7, 0, 1152, 36, 1152, 0, 256);
    }

    // ---- frame L3, L4 (convp 4-phase interleaved) ----
    //       inP  Wp   bias  out  ICsh IWp inSS    OWsh OWpo outSS  pad nt Kpad relu npt OCtot
    convp_k<128,256,2,4,2><<<256, 512, 0, stream>>>(f2p, Wp3, bb[3], f3p, 6, 66, 278784, 5, 34, 147968, 1,  9,  576, 1, 4, 128);
    convp_k<256,256,2,4,1><<<256, 512, 0, stream>>>(f3p, Wp4, bb[4], ffm, 7, 34, 147968, 5, 32, 262144, 0, 18, 1152, 0, 4, 256);

    // ---- xcorr (MFMA) + band-reduce + BN ----
    xcmf_k<<<400, 256, 0, stream>>>(ffm, cfm, Rbuf);
    xred_k<<<157, 256, 0, stream>>>(Rbuf, part);
    bn_k<<<1, 1024, 0, stream>>>(part, gamma, beta, out);
}

// Round 11
// 269.795 us; speedup vs baseline: 1.1976x; 1.1130x over previous
//
#include <hip/hip_runtime.h>

// ---------------------------------------------------------------------------
// CorrelationalDetector R11 (= R10 with coalesced staging in convp):
//  convp_k now uses a swizzled ROW-MAJOR LDS layout: slot s holds
//  (row = s>>3, oct = (s&7)^((s>>3)&7)). A staging wave's 64 slots map to
//  8 rows x 128B contiguous global memory -> 8 transactions per
//  global_load_lds instead of 64 (R10 mapped consecutive lanes to
//  consecutive rows at 256-2304B stride = 64-way gather). The XOR keeps
//  ds_read_b128 at 2-way bank aliasing (free, m136).
//  Pieces are row-ranges now, so ONE wait+barrier per K-tile at p0
//  (vmcnt(AH) after issuing next-tile A-h0 retires the whole current tile);
//  staging pieces still spread over the 4 phases; trailing barrier at p3.
//  Everything else byte-identical to R10.
// ---------------------------------------------------------------------------

typedef __bf16 bf16x8 __attribute__((ext_vector_type(8)));
typedef float f32x4 __attribute__((ext_vector_type(4)));
typedef unsigned int u32x4 __attribute__((ext_vector_type(4)));
typedef unsigned int u32x2 __attribute__((ext_vector_type(2)));
typedef unsigned short u16;

#define AS1 __attribute__((address_space(1)))
#define AS3 __attribute__((address_space(3)))

__device__ __forceinline__ u16 f2bf(float v) {
    unsigned u = __float_as_uint(v);
    u += 0x7fffu + ((u >> 16) & 1u);          // RNE
    return (u16)(u >> 16);
}

__device__ __forceinline__ bf16x8 ldb8(const u16* p) {
    return *(const bf16x8*)p;
}

__device__ __forceinline__ bf16x8 zerob8() {
    u32x4 z = {0u, 0u, 0u, 0u};
    bf16x8 r;
    __builtin_memcpy(&r, &z, 16);
    return r;
}

__device__ __forceinline__ void gload16(const u16* g, u16* l) {
    __builtin_amdgcn_global_load_lds((const AS1 void*)g, (AS3 void*)l, 16, 0, 0);
}

template<int N> __device__ __forceinline__ void wait_vm() {
    asm volatile("s_waitcnt vmcnt(%0)" :: "i"(N) : "memory");
}

__device__ __forceinline__ void bar_mem() {
    asm volatile("" ::: "memory");
    __builtin_amdgcn_s_barrier();
    asm volatile("" ::: "memory");
}

// per-side geometry for merged / CP-parameterized conv kernels
struct CP { const u16* in; u16* out; int IWp, inSS, OWsh, OWpo, outSS, npt; };

// ---- merged halo zero ------------------------------------------------------
struct HZd { unsigned long long ptr; int B, Hp, Wpx, w8, cum; };
struct HZall { HZd d[8]; int total; };

__global__ __launch_bounds__(256)
void haloz_k(HZall h)
{
    for (int i = blockIdx.x * 256 + threadIdx.x; i < h.total; i += gridDim.x * 256) {
        int di = 0;
        #pragma unroll
        for (int j = 1; j < 8; ++j) if (i >= h.d[j].cum) di = j;
        const HZd D = h.d[di];
        const int loc = i - D.cum;
        const int w = loc % D.w8; int t2 = loc / D.w8;
        const int bord = 2 * D.Wpx + 2 * (D.Hp - 2);
        const int pb = t2 % bord; const int b = t2 / bord;
        int oh, ow;
        if (pb < D.Wpx)            { oh = 0;        ow = pb; }
        else if (pb < 2 * D.Wpx)   { oh = D.Hp - 1; ow = pb - D.Wpx; }
        else { const int q = pb - 2 * D.Wpx; oh = 1 + (q >> 1); ow = (q & 1) ? (D.Wpx - 1) : 0; }
        ((unsigned long long*)D.ptr)[((size_t)b * D.Hp * D.Wpx + (size_t)oh * D.Wpx + ow) * D.w8 + w] = 0ull;
    }
}

// ---- merged weight pack ----------------------------------------------------
__device__ __forceinline__ void packone(const float* W, u16* Wp, int idx,
                                        int ICsh, int Kpad)
{
    const int k = idx % Kpad, oc = idx / Kpad;
    const int tap = k >> ICsh, ic = k & ((1 << ICsh) - 1);
    const float v = (tap < 9) ? W[((size_t)(oc << ICsh) + ic) * 9 + tap] : 0.f;
    Wp[idx] = f2bf(v);
}

__global__ __launch_bounds__(256)
void packall_k(const float* __restrict__ W1, const float* __restrict__ W2,
               const float* __restrict__ W3, const float* __restrict__ W4,
               u16* __restrict__ Wc1, u16* __restrict__ Wp2,
               u16* __restrict__ Wp3, u16* __restrict__ Wp4)
{
    const int i = blockIdx.x * 256 + threadIdx.x;
    if (i < 1024) {                       // Wc1: [16][64], k = ky*16+kx*4+ic
        const int k = i & 63, oc = i >> 6;
        const int ky = k >> 4, kx = (k >> 2) & 3, ic = k & 3;
        const float v = (ky < 3 && kx < 3 && ic < 3) ? W1[oc * 27 + ic * 9 + ky * 3 + kx] : 0.f;
        Wc1[i] = f2bf(v);
    } else if (i < 11264) {               // 1024 + 64*160
        packone(W2, Wp2, i - 1024, 4, 160);
    } else if (i < 84992) {               // + 128*576
        packone(W3, Wp3, i - 11264, 6, 576);
    } else if (i < 379904) {              // + 256*1152
        packone(W4, Wp4, i - 84992, 7, 1152);
    }
}

// ---- L0 body ----------------------------------------------------------------
__device__ __forceinline__ void conv0_body(const float* __restrict__ in,
                                           const float* __restrict__ W,
                                           const float* __restrict__ bias,
                                           u16* __restrict__ outP,
                                           int IH, int IW, int OH, int OW, int idx)
{
    const int OW4 = OW >> 2;
    const int OWp = OW + 2, OHp = OH + 2;
    const int ow4 = idx % OW4; int t = idx / OW4;
    const int oh = t % OH;  const int b = t / OH;
    const int owb = ow4 * 4;
    float a0[4], a1[4], a2[4];
    #pragma unroll
    for (int j = 0; j < 4; ++j) { a0[j] = bias[0]; a1[j] = bias[1]; a2[j] = bias[2]; }
    const float* inb = in + (size_t)b * 3 * IH * IW;
    const int xbase = owb * 2 - 1;
    #pragma unroll
    for (int ic = 0; ic < 3; ++ic) {
        const float* ip = inb + (size_t)ic * IH * IW;
        #pragma unroll
        for (int ky = 0; ky < 3; ++ky) {
            const int y = oh * 2 - 1 + ky;
            if ((unsigned)y >= (unsigned)IH) continue;
            const float* rp = ip + (size_t)y * IW;
            float xr[9];
            #pragma unroll
            for (int i2 = 0; i2 < 9; ++i2) {
                const int x = xbase + i2;
                xr[i2] = ((unsigned)x < (unsigned)IW) ? rp[x] : 0.f;
            }
            #pragma unroll
            for (int kx = 0; kx < 3; ++kx) {
                const float w0 = W[0 * 27 + ic * 9 + ky * 3 + kx];
                const float w1 = W[1 * 27 + ic * 9 + ky * 3 + kx];
                const float w2 = W[2 * 27 + ic * 9 + ky * 3 + kx];
                #pragma unroll
                for (int j = 0; j < 4; ++j) {
                    const float xv = xr[2 * j + kx];
                    a0[j] += xv * w0; a1[j] += xv * w1; a2[j] += xv * w2;
                }
            }
        }
    }
    u16* op = outP + (((size_t)b * OHp + oh + 1) * OWp + owb + 1) * 4;
    #pragma unroll
    for (int j = 0; j < 4; ++j) {
        u32x2 pk;
        pk[0] = (unsigned)f2bf(fmaxf(a0[j], 0.f)) | ((unsigned)f2bf(fmaxf(a1[j], 0.f)) << 16);
        pk[1] = (unsigned)f2bf(fmaxf(a2[j], 0.f));
        *(u32x2*)(op + j * 4) = pk;
    }
}

__global__ __launch_bounds__(256)
void conv0m_k(const float* __restrict__ crop, const float* __restrict__ frame,
              const float* __restrict__ W, const float* __restrict__ bias,
              u16* __restrict__ c0b, u16* __restrict__ f0b)
{
    if (blockIdx.x < 64)
        conv0_body(crop, W, bias, c0b, 64, 64, 32, 32, blockIdx.x * 256 + threadIdx.x);
    else
        conv0_body(frame, W, bias, f0b, 256, 256, 128, 128, (blockIdx.x - 64) * 256 + threadIdx.x);
}

// ---- L1 body: MFMA GEMM M=16 oc, K=64 --------------------------------------
__device__ __forceinline__ void conv1g_body(const u16* __restrict__ inP,
                                            const u16* __restrict__ Wc1,
                                            const float* __restrict__ bias,
                                            u16* __restrict__ outP,
                                            int IWp, int inSS, int OWp, int outSS,
                                            int OWsh, int HWsh, int w, int lane)
{
    const int lr = lane & 15, lg = lane >> 4;
    const int pxb = w * 64;
    const int OW = 1 << OWsh;

    const bf16x8 av0 = ldb8(Wc1 + lr * 64 + lg * 8);
    const bf16x8 av1 = ldb8(Wc1 + lr * 64 + 32 + lg * 8);
    const int ky0 = lg >> 1, kxb = (lg & 1) * 2;
    const int ky1 = 2 + (lg >> 1);

    f32x4 acc[4] = {};
    #pragma unroll
    for (int n = 0; n < 4; ++n) {
        const int px = pxb + n * 16 + lr;
        const int b = px >> HWsh;
        const int rem = px & ((1 << HWsh) - 1);
        const int oh = rem >> OWsh, ow = rem & (OW - 1);
        const u16* ib = inP + (size_t)b * inSS + (((size_t)(oh * 2)) * IWp + ow * 2) * 4;
        const bf16x8 bv0 = ldb8(ib + ((size_t)ky0 * IWp + kxb) * 4);
        acc[n] = __builtin_amdgcn_mfma_f32_16x16x32_bf16(av0, bv0, acc[n], 0, 0, 0);
        const bf16x8 bv1 = ldb8(ib + ((size_t)ky1 * IWp + kxb) * 4);
        acc[n] = __builtin_amdgcn_mfma_f32_16x16x32_bf16(av1, bv1, acc[n], 0, 0, 0);
    }

    const float b0 = bias[lg * 4], b1 = bias[lg * 4 + 1],
                b2 = bias[lg * 4 + 2], b3 = bias[lg * 4 + 3];
    #pragma unroll
    for (int n = 0; n < 4; ++n) {
        const int px = pxb + n * 16 + lr;
        const int b = px >> HWsh;
        const int rem = px & ((1 << HWsh) - 1);
        const int oh = rem >> OWsh, ow = rem & (OW - 1);
        const f32x4 a = acc[n];
        u32x2 pk;
        pk[0] = (unsigned)f2bf(fmaxf(a[0] + b0, 0.f)) | ((unsigned)f2bf(fmaxf(a[1] + b1, 0.f)) << 16);
        pk[1] = (unsigned)f2bf(fmaxf(a[2] + b2, 0.f)) | ((unsigned)f2bf(fmaxf(a[3] + b3, 0.f)) << 16);
        u16* op = outP + (size_t)b * outSS + (((size_t)(oh + 1)) * OWp + (ow + 1)) * 16 + lg * 4;
        *(u32x2*)op = pk;
    }
}

__global__ __launch_bounds__(256)
void conv1m_k(const u16* __restrict__ c0b, u16* __restrict__ c1p,
              const u16* __restrict__ f0b, u16* __restrict__ f1p,
              const u16* __restrict__ Wc1, const float* __restrict__ bias)
{
    const int wv = threadIdx.x >> 6, lane = threadIdx.x & 63;
    if (blockIdx.x < 64)
        conv1g_body(c0b, Wc1, bias, c1p, 34, 4624, 18, 5184, 4, 8, blockIdx.x * 4 + wv, lane);
    else
        conv1g_body(f0b, Wc1, bias, f1p, 130, 67600, 66, 69696, 6, 12, (blockIdx.x - 64) * 4 + wv, lane);
}

// ---- convp: 4-phase interleaved MFMA conv GEMM, COALESCED staging ----------
// LDS layout (A and B): slot s holds (row = s>>3, oct = (s&7)^((s>>3)&7)).
// A staging wave reads 8 rows x 128B contiguous (8 tx). ds_read fragment
// (row R, oct kk*4+lg): slot = R*8 + ((kk*4+lg)^(R&7)); R&7==lr&7 -> 2-way
// bank aliasing (free). One wait+barrier per K-tile at p0 (vmcnt(AH) after
// issuing next-tile A-h0 retires ALL of the current tile across this wave;
// barrier makes all waves' staging visible). Trailing barrier at p3 keeps
// next-tile writes off buffers still being read.
template<int BM, int BN, int NWM, int NWN, int S>
__global__ __launch_bounds__(512, 2)
void convp_k(const u16* __restrict__ inP, const u16* __restrict__ Wp,
             const float* __restrict__ bias, u16* __restrict__ out,
             int IC_sh, int IWp, int inSS, int OW_sh, int OWp_o, int outSS,
             int pad_o, int nt, int Kpad, int relu, int n_pt, int OCtot)
{
    constexpr int MF = BM / (NWM * 16);
    constexpr int NF = BN / (NWN * 16);
    constexpr int MH = MF / 2;
    constexpr int ASLOT = BM * 8;          // 16B slots per buffer (BK=64)
    constexpr int BSLOT = BN * 8;
    constexpr int AISS = ASLOT / 512;      // per-thread A loads per tile
    constexpr int BISS = BSLOT / 512;
    constexpr int AH = AISS / 2, BH = BISS / 2;

    __shared__ __align__(16) u16 Ab[2][ASLOT * 8];
    __shared__ __align__(16) u16 Bb[2][BSLOT * 8];

    const int t    = threadIdx.x;
    const int wv   = t >> 6, lane = t & 63;
    const int lr   = lane & 15, lg = lane >> 4;
    const int lr7  = lr & 7;
    const int wm   = wv / NWN, wn = wv % NWN;

    const int tilesPerB = (OCtot / BM) * n_pt;
    const int b  = blockIdx.x / tilesPerB;
    const int r0 = blockIdx.x - b * tilesPerB;
    const int mt = r0 / n_pt, pt = r0 - mt * n_pt;
    const int ocb = mt * BM, pxb = pt * BN;
    const int IC = 1 << IC_sh;
    const int OW = 1 << OW_sh;

    const u16* __restrict__ inb = inP + (size_t)b * inSS;

    // staging geometry: slot s = i*512 + t -> row s>>3, oct (s&7)^((s>>3)&7)
    const u16* agp[AISS];
    #pragma unroll
    for (int i = 0; i < AISS; ++i) {
        const int s = i * 512 + t;
        const int r = s >> 3;
        const int oct = (s & 7) ^ (r & 7);
        agp[i] = Wp + (size_t)(ocb + r) * Kpad + oct * 8;
    }
    const u16* bpx[BISS];
    #pragma unroll
    for (int i = 0; i < BISS; ++i) {
        const int s = i * 512 + t;
        const int p = s >> 3;
        const int oct = (s & 7) ^ (p & 7);
        const int px = pxb + p;
        const int oh = px >> OW_sh, ow = px & (OW - 1);
        bpx[i] = inb + ((size_t)(oh * S) * IWp + ow * S) * IC + oct * 8;
    }

    f32x4 acc[MF][NF] = {};

    auto STAGE_A = [&](int buf, int kb, int h) {
        #pragma unroll
        for (int i = h * AH; i < (h + 1) * AH; ++i)
            gload16(agp[i] + kb, &Ab[buf][(size_t)(i * 512 + t) * 8]);
    };
    auto STAGE_B = [&](int buf, int kb, int h) {
        const int tap = kb >> IC_sh;          // uniform: BK=64 <= IC
        const int ky = (tap * 11) >> 5, kx = tap - 3 * ky;
        const size_t toff = ((size_t)(ky * IWp + kx) << IC_sh) + (kb & (IC - 1));
        #pragma unroll
        for (int i = h * BH; i < (h + 1) * BH; ++i)
            gload16(bpx[i] + toff, &Bb[buf][(size_t)(i * 512 + t) * 8]);
    };

    // prologue: tile 0 fully staged
    STAGE_A(0, 0, 0); STAGE_B(0, 0, 0); STAGE_A(0, 0, 1); STAGE_B(0, 0, 1);

    for (int ks = 0; ks < nt; ++ks) {
        const int cur = ks & 1, nxt = cur ^ 1;
        const int kb1 = (ks + 1) * 64;
        const bool pf = (ks + 1 < nt);
        bf16x8 bfc[NF], af[MH];

        // slot helpers for this tile's fragments (row-major swizzled)
        // A row base (per m): Ra = wm*MF*16 + m*16 + lr ; B row: Pb = wn*NF*16 + n*16 + lr
        // ---- p0: kk=0, mh=0 ----
        if (pf) { STAGE_A(nxt, kb1, 0); wait_vm<AH>(); }
        else    { wait_vm<0>(); }
        bar_mem();                            // whole tile ks visible to all waves
        {
            const int octv = lg ^ lr7;        // kk=0
            #pragma unroll
            for (int n = 0; n < NF; ++n) {
                const int P = wn * (NF * 16) + n * 16 + lr;
                bfc[n] = ldb8(&Bb[cur][(size_t)(P * 8 + octv) * 8]);
            }
            #pragma unroll
            for (int m = 0; m < MH; ++m) {
                const int R = wm * (MF * 16) + m * 16 + lr;
                af[m] = ldb8(&Ab[cur][(size_t)(R * 8 + octv) * 8]);
            }
        }
        __builtin_amdgcn_s_setprio(1);
        #pragma unroll
        for (int m = 0; m < MH; ++m)
            #pragma unroll
            for (int n = 0; n < NF; ++n)
                acc[m][n] = __builtin_amdgcn_mfma_f32_16x16x32_bf16(af[m], bfc[n], acc[m][n], 0, 0, 0);
        __builtin_amdgcn_s_setprio(0);

        // ---- p1: kk=0, mh=1 (bfc reused) ----
        if (pf) STAGE_B(nxt, kb1, 0);
        {
            const int octv = lg ^ lr7;
            #pragma unroll
            for (int m = 0; m < MH; ++m) {
                const int R = wm * (MF * 16) + (MH + m) * 16 + lr;
                af[m] = ldb8(&Ab[cur][(size_t)(R * 8 + octv) * 8]);
            }
        }
        __builtin_amdgcn_s_setprio(1);
        #pragma unroll
        for (int m = 0; m < MH; ++m)
            #pragma unroll
            for (int n = 0; n < NF; ++n)
                acc[MH + m][n] = __builtin_amdgcn_mfma_f32_16x16x32_bf16(af[m], bfc[n], acc[MH + m][n], 0, 0, 0);
        __builtin_amdgcn_s_setprio(0);

        // ---- p2: kk=1, mh=0 ----
        if (pf) STAGE_A(nxt, kb1, 1);
        {
            const int octv = (4 + lg) ^ lr7;  // kk=1
            #pragma unroll
            for (int n = 0; n < NF; ++n) {
                const int P = wn * (NF * 16) + n * 16 + lr;
                bfc[n] = ldb8(&Bb[cur][(size_t)(P * 8 + octv) * 8]);
            }
            #pragma unroll
            for (int m = 0; m < MH; ++m) {
                const int R = wm * (MF * 16) + m * 16 + lr;
                af[m] = ldb8(&Ab[cur][(size_t)(R * 8 + octv) * 8]);
            }
        }
        __builtin_amdgcn_s_setprio(1);
        #pragma unroll
        for (int m = 0; m < MH; ++m)
            #pragma unroll
            for (int n = 0; n < NF; ++n)
                acc[m][n] = __builtin_amdgcn_mfma_f32_16x16x32_bf16(af[m], bfc[n], acc[m][n], 0, 0, 0);
        __builtin_amdgcn_s_setprio(0);

        // ---- p3: kk=1, mh=1 ----
        if (pf) STAGE_B(nxt, kb1, 1);
        {
            const int octv = (4 + lg) ^ lr7;
            #pragma unroll
            for (int m = 0; m < MH; ++m) {
                const int R = wm * (MF * 16) + (MH + m) * 16 + lr;
                af[m] = ldb8(&Ab[cur][(size_t)(R * 8 + octv) * 8]);
            }
        }
        __builtin_amdgcn_s_setprio(1);
        #pragma unroll
        for (int m = 0; m < MH; ++m)
            #pragma unroll
            for (int n = 0; n < NF; ++n)
                acc[MH + m][n] = __builtin_amdgcn_mfma_f32_16x16x32_bf16(af[m], bfc[n], acc[MH + m][n], 0, 0, 0);
        __builtin_amdgcn_s_setprio(0);
        bar_mem();                            // protect cur from next tile's writes
    }

    #pragma unroll
    for (int m = 0; m < MF; ++m) {
        const int oc0 = ocb + wm * (MF * 16) + m * 16 + lg * 4;
        const float b0 = bias[oc0], b1 = bias[oc0 + 1], b2 = bias[oc0 + 2], b3 = bias[oc0 + 3];
        #pragma unroll
        for (int n = 0; n < NF; ++n) {
            const int px = pxb + wn * (NF * 16) + n * 16 + lr;
            const int oh = px >> OW_sh, ow = px & (OW - 1);
            const f32x4 a = acc[m][n];
            float v0 = a[0] + b0, v1 = a[1] + b1, v2 = a[2] + b2, v3 = a[3] + b3;
            if (relu) {
                v0 = fmaxf(v0, 0.f); v1 = fmaxf(v1, 0.f);
                v2 = fmaxf(v2, 0.f); v3 = fmaxf(v3, 0.f);
            }
            u32x2 pk;
            pk[0] = (unsigned)f2bf(v0) | ((unsigned)f2bf(v1) << 16);
            pk[1] = (unsigned)f2bf(v2) | ((unsigned)f2bf(v3) << 16);
            u16* op = out + (size_t)b * outSS +
                      (((size_t)(oh + pad_o)) * OWp_o + (ow + pad_o)) * (size_t)OCtot + oc0;
            *(u32x2*)op = pk;
        }
    }
}

// ---- convg3: 4-buffer 3-deep pipeline, CP-parameterized --------------------
template<int BM, int BN, int NWM, int NWN, int S>
__global__ __launch_bounds__(256, 2)
void convg3_k(CP A, CP B, int split,
              const u16* __restrict__ Wp, const float* __restrict__ bias,
              int IC_sh, int pad_o, int Kreal, int nt, int Kpad, int relu, int OCtot)
{
    constexpr int MF = BM / (NWM * 16);
    constexpr int NF = BN / (NWN * 16);
    constexpr int ASLOT = BM * 4;
    constexpr int BSLOT = BN * 4;
    constexpr int AISS = ASLOT / 256;
    constexpr int BISS = BSLOT / 256;
    constexpr int NSTG = AISS + BISS;

    __shared__ __align__(16) u16 Ab[4][ASLOT * 8];
    __shared__ __align__(16) u16 Bb[4][BSLOT * 8];

    CP P; int bid;
    if (blockIdx.x < (unsigned)split) { P = A; bid = blockIdx.x; }
    else                              { P = B; bid = blockIdx.x - split; }

    const int t    = threadIdx.x;
    const int wv   = t >> 6, lane = t & 63;
    const int lr   = lane & 15, lg = lane >> 4;
    const int wm   = wv / NWN, wn = wv % NWN;

    const int tilesPerB = (OCtot / BM) * P.npt;
    const int b  = bid / tilesPerB;
    const int r0 = bid - b * tilesPerB;
    const int mt = r0 / P.npt, pt = r0 - mt * P.npt;
    const int ocb = mt * BM, pxb = pt * BN;
    const int IC = 1 << IC_sh;
    const int OW = 1 << P.OWsh;

    const u16* __restrict__ inb = P.in + (size_t)b * P.inSS;

    const u16* agp[AISS];
    #pragma unroll
    for (int i = 0; i < AISS; ++i) {
        const int s = i * 256 + t;
        const int q = s / BM, rr = s - q * BM;
        agp[i] = Wp + (size_t)(ocb + rr) * Kpad + q * 8;
    }
    int bq[BISS]; const u16* bpx[BISS];
    #pragma unroll
    for (int i = 0; i < BISS; ++i) {
        const int s = i * 256 + t;
        const int q = s / BN, rr = s - q * BN;
        const int px = pxb + rr;
        const int oh = px >> P.OWsh, ow = px & (OW - 1);
        bq[i] = q;
        bpx[i] = inb + ((size_t)(oh * S) * P.IWp + ow * S) * IC;
    }

    f32x4 acc[MF][NF] = {};

    auto STAGE = [&](int buf, int kb) {
        #pragma unroll
        for (int i = 0; i < AISS; ++i)
            gload16(agp[i] + kb, &Ab[buf][(size_t)(i * 256 + wv * 64) * 8]);
        #pragma unroll
        for (int i = 0; i < BISS; ++i) {
            const int k = kb + bq[i] * 8;
            const int tap = k >> IC_sh;
            const int ic = k & (IC - 1);
            const int ky = (tap * 11) >> 5, kx = tap - 3 * ky;
            const u16* g = bpx[i] + ((size_t)ky * P.IWp + kx) * IC + ic;
            if (k >= Kreal) g = inb;           // zero weights there; any in-bounds addr
            gload16(g, &Bb[buf][(size_t)(i * 256 + wv * 64) * 8]);
        }
    };

    STAGE(0, 0);
    if (1 < nt) STAGE(1, 32);
    if (2 < nt) STAGE(2, 64);

    for (int ks = 0; ks < nt; ++ks) {
        const int rem = nt - 1 - ks;
        if (rem >= 2)      wait_vm<2 * NSTG>();
        else if (rem == 1) wait_vm<NSTG>();
        else               wait_vm<0>();
        bar_mem();
        if (ks + 3 < nt) STAGE((ks + 3) & 3, (ks + 3) * 32);

        const int cur = ks & 3;
        bf16x8 af[MF], bf_[NF];
        #pragma unroll
        for (int m = 0; m < MF; ++m)
            af[m] = ldb8(&Ab[cur][(size_t)(lg * BM + wm * (MF * 16) + m * 16 + lr) * 8]);
        #pragma unroll
        for (int n = 0; n < NF; ++n)
            bf_[n] = ldb8(&Bb[cur][(size_t)(lg * BN + wn * (NF * 16) + n * 16 + lr) * 8]);

        __builtin_amdgcn_s_setprio(1);
        #pragma unroll
        for (int m = 0; m < MF; ++m)
            #pragma unroll
            for (int n = 0; n < NF; ++n)
                acc[m][n] = __builtin_amdgcn_mfma_f32_16x16x32_bf16(af[m], bf_[n], acc[m][n], 0, 0, 0);
        __builtin_amdgcn_s_setprio(0);
    }

    #pragma unroll
    for (int m = 0; m < MF; ++m) {
        const int oc0 = ocb + wm * (MF * 16) + m * 16 + lg * 4;
        const float b0 = bias[oc0], b1 = bias[oc0 + 1], b2 = bias[oc0 + 2], b3 = bias[oc0 + 3];
        #pragma unroll
        for (int n = 0; n < NF; ++n) {
            const int px = pxb + wn * (NF * 16) + n * 16 + lr;
            const int oh = px >> P.OWsh, ow = px & (OW - 1);
            const f32x4 a = acc[m][n];
            float v0 = a[0] + b0, v1 = a[1] + b1, v2 = a[2] + b2, v3 = a[3] + b3;
            if (relu) {
                v0 = fmaxf(v0, 0.f); v1 = fmaxf(v1, 0.f);
                v2 = fmaxf(v2, 0.f); v3 = fmaxf(v3, 0.f);
            }
            u32x2 pk;
            pk[0] = (unsigned)f2bf(v0) | ((unsigned)f2bf(v1) << 16);
            pk[1] = (unsigned)f2bf(v2) | ((unsigned)f2bf(v3) << 16);
            u16* op = P.out + (size_t)b * P.outSS +
                      (((size_t)(oh + pad_o)) * P.OWpo + (ow + pad_o)) * (size_t)OCtot + oc0;
            *(u32x2*)op = pk;
        }
    }
}

// ---- xcorr as batched MFMA GEMM --------------------------------------------
__global__ __launch_bounds__(256)
void xcmf_k(const u16* __restrict__ ffm, const u16* __restrict__ cfm,
            float* __restrict__ R)
{
    const int w    = blockIdx.x * 4 + (threadIdx.x >> 6);   // 1600 waves
    const int lane = threadIdx.x & 63;
    const int lr   = lane & 15, lg = lane >> 4;
    const int b  = w / 25;
    const int tp = w - b * 25;

    const int col0 = tp * 32 + lr;
    const int col1 = col0 + 16;
    const int y0 = col0 / 25, x0 = col0 - y0 * 25;
    const int y1 = col1 / 25, x1 = col1 - y1 * 25;

    const u16* fb = ffm + (size_t)b * 262144;
    const u16* f0 = fb + ((size_t)y0 * 32 + x0) * 256 + lg * 8;
    const u16* f1 = fb + ((size_t)y1 * 32 + x1) * 256 + lg * 8;
    const u16* ab = cfm + (size_t)b * 16384 + (size_t)lr * 2048 + lg * 8;
    const bool arow = (lr < 8);

    f32x4 acc0 = {}, acc1 = {};
    #pragma unroll 4
    for (int kb = 0; kb < 2048; kb += 32) {
        const bf16x8 av = arow ? ldb8(ab + kb) : zerob8();
        const bf16x8 bv0 = ldb8(f0 + kb);
        const bf16x8 bv1 = ldb8(f1 + kb);
        acc0 = __builtin_amdgcn_mfma_f32_16x16x32_bf16(av, bv0, acc0, 0, 0, 0);
        acc1 = __builtin_amdgcn_mfma_f32_16x16x32_bf16(av, bv1, acc1, 0, 0, 0);
    }

    if (lg < 2) {
        float* rb = R + (size_t)b * 6400;
        #pragma unroll
        for (int j = 0; j < 4; ++j) {
            const int d = lg * 4 + j;
            rb[(size_t)d * 800 + col0] = acc0[j];
            rb[(size_t)d * 800 + col1] = acc1[j];
        }
    }
}

// ---- diagonal-band reduce --------------------------------------------------
__global__ __launch_bounds__(256)
void xred_k(const float* __restrict__ R, float* __restrict__ part)
{
    const int i = blockIdx.x * 256 + threadIdx.x;
    if (i >= 40000) return;
    const int b = i / 625;
    const int o = i - b * 625;
    const float* rb = R + (size_t)b * 6400 + o;
    float v = 0.f;
    #pragma unroll
    for (int d = 0; d < 8; ++d) v += rb[(size_t)d * 800 + d * 25];
    part[i] = v;
}

// ---- BatchNorm over all 40000 elements -------------------------------------
__global__ __launch_bounds__(1024)
void bn_k(const float* __restrict__ rmap, const float* __restrict__ gamma,
          const float* __restrict__ beta, float* __restrict__ out)
{
    const int N = 40000;
    const int tid = threadIdx.x;
    __shared__ float rs[1024], rq[1024];
    __shared__ float mean_s, inv_s;
    float s = 0.f, q = 0.f;
    for (int i = tid; i < N; i += 1024) {
        const float v = rmap[i];
        s += v; q += v * v;
    }
    rs[tid] = s; rq[tid] = q;
    __syncthreads();
    for (int off = 512; off > 0; off >>= 1) {
        if (tid < off) { rs[tid] += rs[tid + off]; rq[tid] += rq[tid + off]; }
        __syncthreads();
    }
    if (tid == 0) {
        const float m = rs[0] / (float)N;
        mean_s = m;
        inv_s = rsqrtf(rq[0] / (float)N - m * m + 1e-5f);
    }
    __syncthreads();
    const float g = gamma[0], bt = beta[0];
    for (int i = tid; i < N; i += 1024)
        out[i] = (rmap[i] - mean_s) * inv_s * g + bt;
}

// ---------------------------------------------------------------------------

extern "C" void kernel_launch(void* const* d_in, const int* in_sizes, int n_in,
                              void* d_out, int out_size, void* d_ws, size_t ws_size,
                              hipStream_t stream)
{
    (void)in_sizes; (void)n_in; (void)out_size; (void)ws_size;
    const float* crop  = (const float*)d_in[0];
    const float* frame = (const float*)d_in[1];
    const float* W[5]; const float* bb[5];
    for (int i = 0; i < 5; ++i) { W[i] = (const float*)d_in[2 + 2*i]; bb[i] = (const float*)d_in[3 + 2*i]; }
    const float* gamma = (const float*)d_in[12];
    const float* beta  = (const float*)d_in[13];
    float* out = (float*)d_out;

    unsigned char* ws = (unsigned char*)d_ws;
    // frame pipeline (sizes in BYTES):
    u16*   f0b  = (u16*)(ws + 0);             // [64][130][130][4]   8,652,800 B (dead after fL1)
    u16*   f1p  = (u16*)(ws + 8652800);       // [64][66][66][16]    8,921,088 B (dead after fL2)
    u16*   f2p  = (u16*)(ws + 17573888);      // [64][66][66][64]   35,684,352 B (dead after fL3)
    u16*   f3p  = (u16*)(ws + 53258240);      // [64][34][34][128]  18,939,904 B
    u16*   ffm  = (u16*)(ws + 0);             // [64][32][32][256]  33,554,432 B (aliases dead f0b..f2p)
    // crop pipeline + weights + xcorr after f3p (ends 72,198,144):
    u16*   c0b  = (u16*)(ws + 72198144);      // [64][34][34][4]       591,872 B
    u16*   c1p  = (u16*)(ws + 72790016);      // [64][18][18][16]      663,552 B
    u16*   c2p  = (u16*)(ws + 73453568);      // [64][18][18][64]    2,654,208 B
    u16*   c3p  = (u16*)(ws + 76107776);      // [64][10][10][128]   1,638,400 B
    u16*   cfm  = (u16*)(ws + 77746176);      // [64][8][8][256]     2,097,152 B
    u16*   Wc1  = (u16*)(ws + 79843328);      // [16][64]                2,048 B
    u16*   Wp2  = (u16*)(ws + 79845376);      // [64][160]              20,480 B
    u16*   Wp3  = (u16*)(ws + 79865856);      // [128][576]            147,456 B
    u16*   Wp4  = (u16*)(ws + 80013312);      // [256][1152]           589,824 B
    float* Rbuf = (float*)(ws + 80603136);    // [64][8][800] f32    1,638,400 B
    float* part = (float*)(ws + 82241536);    // [40000] f32           160,000 B

    // ---- one merged halo-zero launch ----
    HZall hz;
    const unsigned long long ptrs[8] = {(unsigned long long)c0b, (unsigned long long)c1p,
        (unsigned long long)c2p, (unsigned long long)c3p, (unsigned long long)f0b,
        (unsigned long long)f1p, (unsigned long long)f2p, (unsigned long long)f3p};
    const int Hps[8] = {34, 18, 18, 10, 130, 66, 66, 34};
    const int w8s[8] = {1, 4, 16, 32, 1, 4, 16, 32};
    int cum = 0;
    for (int i = 0; i < 8; ++i) {
        hz.d[i].ptr = ptrs[i]; hz.d[i].B = 64; hz.d[i].Hp = Hps[i];
        hz.d[i].Wpx = Hps[i]; hz.d[i].w8 = w8s[i]; hz.d[i].cum = cum;
        cum += 64 * (2 * Hps[i] + 2 * (Hps[i] - 2)) * w8s[i];
    }
    hz.total = cum;
    haloz_k<<<1024, 256, 0, stream>>>(hz);

    // ---- one merged weight-pack launch ----
    packall_k<<<1484, 256, 0, stream>>>(W[1], W[2], W[3], W[4], Wc1, Wp2, Wp3, Wp4);

    // ---- merged heads (crop+frame): L0, L1, L2 ----
    conv0m_k<<<1088, 256, 0, stream>>>(crop, frame, W[0], bb[0], c0b, f0b);
    conv1m_k<<<1088, 256, 0, stream>>>(c0b, c1p, f0b, f1p, Wc1, bb[1]);
    {
        CP Ac = {c1p, c2p, 18,  5184, 4, 18, 20736,  1};
        CP Bf = {f1p, f2p, 66, 69696, 6, 66, 278784, 16};
        convg3_k<64,256,1,4,1><<<1088, 256, 0, stream>>>(Ac, Bf, 64, Wp2, bb[2],
            4, 1, 144, 5, 160, 1, 64);
    }

    // ---- crop L3, L4 (small, convg3) ----
    {
        CP A3 = {c2p, c3p, 18, 20736, 3, 10, 12800, 1};
        convg3_k<128,64,4,1,2><<<64, 256, 0, stream>>>(A3, A3, 1 << 30, Wp3, bb[3],
            6, 1, 576, 18, 576, 1, 128);
        CP A4 = {c3p, cfm, 10, 12800, 3, 8, 16384, 1};
        convg3_k<256,64,4,1,1><<<64, 256, 0, stream>>>(A4, A4, 1 << 30, Wp4, bb[4],
            7, 0, 1152, 36, 1152, 0, 256);
    }

    // ---- frame L3, L4 (convp coalesced 4-phase) ----
    //       inP  Wp   bias  out  ICsh IWp inSS    OWsh OWpo outSS  pad nt Kpad relu npt OCtot
    convp_k<128,256,2,4,2><<<256, 512, 0, stream>>>(f2p, Wp3, bb[3], f3p, 6, 66, 278784, 5, 34, 147968, 1,  9,  576, 1, 4, 128);
    convp_k<256,256,2,4,1><<<256, 512, 0, stream>>>(f3p, Wp4, bb[4], ffm, 7, 34, 147968, 5, 32, 262144, 0, 18, 1152, 0, 4, 256);

    // ---- xcorr (MFMA) + band-reduce + BN ----
    xcmf_k<<<400, 256, 0, stream>>>(ffm, cfm, Rbuf);
    xred_k<<<157, 256, 0, stream>>>(Rbuf, part);
    bn_k<<<1, 1024, 0, stream>>>(part, gamma, beta, out);
}